// Round 8
// baseline (424.590 us; speedup 1.0000x reference)
//
#include <hip/hip_runtime.h>

// Problem constants (fixed by setup_inputs)
#define BG    4        // num_graphs
#define TT    12       // timesteps
#define NN    10000    // nodes per graph
#define EN    200000   // membership entries
#define NSEG  40000    // n*B segments
#define NROWS 40000    // B*n output rows
#define MPAD  40064    // 313*128
#define KD    800      // padded in_dim (780 -> 800 = 25*32)
#define KA0   160      // padded K for layer0 GEMM: 12 features + 128 Cf + 20 zero
#define NPW   896      // padded N for weight tiles (7*128)
#define NT    7        // N-tiles per row panel (NPW/128)

typedef __attribute__((ext_vector_type(8))) short bf8_t;   // 8 bf16 (4 VGPR) MFMA A/B frag
typedef __attribute__((ext_vector_type(4))) float f4_t;    // 4 f32 MFMA C/D frag

__device__ __forceinline__ unsigned short f2bf(float x) {  // RNE f32->bf16
  unsigned int u = __float_as_uint(x);
  u += 0x7fffu + ((u >> 16) & 1u);
  return (unsigned short)(u >> 16);
}

#define GLDS16(src, dst) __builtin_amdgcn_global_load_lds( \
    (const __attribute__((address_space(1))) void*)(src),  \
    (__attribute__((address_space(3))) void*)(dst), 16, 0, 0)

// ---------------- prep ----------------
__global__ void k_zero(int* counts) {
  int i = blockIdx.x * 256 + threadIdx.x;
  if (i < NSEG) counts[i] = 0;
}

__global__ void k_count(const int* __restrict__ mapper, int* __restrict__ counts) {
  int e = blockIdx.x * 256 + threadIdx.x;
  if (e < EN) atomicAdd(&counts[mapper[e]], 1);
}

__global__ void k_zerof(float* __restrict__ p, int n) {
  int i = blockIdx.x * 256 + threadIdx.x;
  if (i < n) p[i] = 0.f;
}

// Cf scatter: entry e contributes 1 to Cff[r][batch[e]], r = output row of segment mapper[e]
__global__ void k_scatterCf(const int* __restrict__ mapper, const int* __restrict__ batch,
                            float* __restrict__ Cff) {
  int e = blockIdx.x * 256 + threadIdx.x;
  if (e < EN) {
    const int s = mapper[e];
    const int r = (s % BG) * NN + s / BG;   // inverse of s = (r%NN)*BG + r/NN
    atomicAdd(&Cff[(size_t)r * 128 + batch[e]], 1.0f);
  }
}

// A = [features(12) | Cf(128) | 0(20)] as bf16, [MPAD][KA0]
__global__ void k_buildA(const float* __restrict__ features, const int* __restrict__ counts,
                         const float* __restrict__ Cff, unsigned short* __restrict__ A) {
  int idx = blockIdx.x * 256 + threadIdx.x;
  if (idx >= MPAD * KA0) return;
  const int r = idx / KA0, c = idx - r * KA0;
  float v = 0.f;
  if (r < NROWS) {
    if (c < 12) {
      v = features[(size_t)r * TT + c];
    } else if (c < 140) {
      const int s = (r % NN) * BG + (r / NN);
      const int cnt = counts[s];
      const float inv = 1.f / (float)(cnt > 0 ? cnt : 1);
      v = Cff[(size_t)r * 128 + (c - 12)] * inv;
    }
  }
  A[idx] = f2bf(v);
}

// B^T for layer0 GEMM: WTB[n][k] = k<12 ? W0[k][n] : k<140 ? fW0[k-12][n] : 0; [NPW][KA0]
__global__ void k_buildB(const float* __restrict__ W0, const float* __restrict__ fW0,
                         unsigned short* __restrict__ WTB) {
  int idx = blockIdx.x * 256 + threadIdx.x;
  if (idx >= NPW * KA0) return;
  const int n = idx / KA0, k = idx - n * KA0;
  float v = 0.f;
  if (n < 780) {
    if (k < 12) v = W0[(size_t)k * 780 + n];
    else if (k < 140) v = fW0[(size_t)(k - 12) * KD + n];
  }
  WTB[idx] = f2bf(v);
}

// Wt[n][k] = W[k][n], zero-padded to [Nrows][KD] bf16. W is [780][ldw].
__global__ void k_tpad(const float* __restrict__ W, unsigned short* __restrict__ Wt,
                       int ldw, int nsrc, int total) {
  int idx = blockIdx.x * 256 + threadIdx.x;
  if (idx >= total) return;
  int n = idx / KD, k = idx % KD;
  float v = (n < nsrc && k < 780) ? W[k * ldw + n] : 0.f;
  Wt[idx] = f2bf(v);
}

// pad b0,b1,b2 -> bp0,bp1,bp2 (KD wide, zeros past 780)
__global__ void k_padbias3(const float* __restrict__ b0, const float* __restrict__ b1,
                           const float* __restrict__ b2, float* __restrict__ p0,
                           float* __restrict__ p1, float* __restrict__ p2) {
  int i = blockIdx.x * 256 + threadIdx.x;
  if (i >= 3 * KD) return;
  const int which = i / KD, c = i - which * KD;
  const float* src = which == 0 ? b0 : (which == 1 ? b1 : b2);
  float* dst = which == 0 ? p0 : (which == 1 ? p1 : p2);
  dst[c] = (c < 780) ? src[c] : 0.f;
}

// flatW0[j][c] = sum_k flat[j][k] * W0[12+k][c], j<128, c<780 (0 for 780<=c<800)
// flat[j][t*64+f] = mixer_x[j%4][t][j/4][f]
// Split-K f32: grid (13 c-tiles x 16 j-tiles), block 256 = 64 c-lanes x 4 k-splits.
__global__ __launch_bounds__(256) void k_flatW0(const float* __restrict__ mixer,
                                                const float* __restrict__ W0,
                                                float* __restrict__ fW0) {
  __shared__ float sA[8][768];       // 24 KB: 8 A-rows
  __shared__ float sRed[4][64][9];   // 9.2 KB, pad 9 -> conflict-free
  const int tid = threadIdx.x;
  const int c0 = blockIdx.x * 64, j0 = blockIdx.y * 8;
  for (int i = tid; i < 8 * 768; i += 256) {
    int jj = i / 768;
    int k = i - jj * 768;
    int j = j0 + jj;
    int tt = k >> 6, ff = k & 63;
    sA[jj][k] = mixer[(((j & 3) * TT + tt) * 32 + (j >> 2)) * 64 + ff];
  }
  __syncthreads();
  const int cc = tid & 63, ks = tid >> 6;
  const int c = c0 + cc;
  float acc[8] = {};
  if (c < 780) {
    const float* wp = W0 + (size_t)(12 + ks * 192) * 780 + c;
    #pragma unroll 4
    for (int k = ks * 192; k < ks * 192 + 192; ++k) {
      const float w = *wp; wp += 780;
      #pragma unroll
      for (int jj = 0; jj < 8; ++jj) acc[jj] = fmaf(sA[jj][k], w, acc[jj]);
    }
  }
  #pragma unroll
  for (int jj = 0; jj < 8; ++jj) sRed[ks][cc][jj] = acc[jj];
  __syncthreads();
  for (int o = tid; o < 512; o += 256) {
    const int oc = o & 63, jj = o >> 6;
    const int wc = c0 + oc;
    if (wc < KD) {
      float s = sRed[0][oc][jj] + sRed[1][oc][jj] + sRed[2][oc][jj] + sRed[3][oc][jj];
      fW0[(size_t)(j0 + jj) * KD + wc] = s;  // cols >=780 stayed 0
    }
  }
}

// ---------------- dense layers: C = relu(A @ W + b), bf16 MFMA ----------------
// A [MPAD][KA] bf16, WT [*][KA] bf16, C [MPAD][KD] bf16 (output stride always KD).
// 128x128 tile, BK=32, 4 waves (2x2), global_load_lds w=16, XCD swizzle (R6).
// R7: double-buffered K-pipeline (T3-minimum, m248 recipe): issue next-tile
// STAGE before computing current tile; single end-of-iteration __syncthreads
// (compiler drains vmcnt there) -> load latency hides under the wave's own
// MFMA instead of relying on TLP. One barrier per K-step instead of two.
// Race: all reads of buf X (iter t-1) retire at that iteration's barrier
// drain; all writes to buf X (iter t) are issued after it.
template<int KA>
__global__ __launch_bounds__(256) void gemm_relu(
    const unsigned short* __restrict__ A, const unsigned short* __restrict__ WT,
    const float* __restrict__ bias, unsigned short* __restrict__ C) {
  __shared__ unsigned short sA[2][128 * 32];
  __shared__ unsigned short sB[2][128 * 32];
  const int tid = threadIdx.x, lane = tid & 63, wid = tid >> 6;
  const int wm = wid >> 1, wn = wid & 1;

  // bijective XCD swizzle (nwg = 313*NT = 2191)
  const int nwg = gridDim.x;
  const int q = nwg >> 3, r8 = nwg & 7;
  const int xcd = blockIdx.x & 7, bidx = blockIdx.x >> 3;
  const int linear = (xcd < r8 ? xcd * (q + 1) : r8 * (q + 1) + (xcd - r8) * q) + bidx;
  const int rowtile = linear / NT, ntile = linear - rowtile * NT;

  const int row0 = rowtile * 128, n0 = ntile * 128;
  const char* gA = (const char*)A + (size_t)row0 * (KA * 2);
  const char* gB = (const char*)WT + (size_t)n0 * (KA * 2);
  const int frow = lane & 15, fk = (lane >> 4) * 8;

  // staging addresses (hoisted): two 256-segment halves, 16B per lane
  const int seg0 = wid * 64 + lane;
  const int seg1 = 256 + wid * 64 + lane;
  const size_t roff0 = (size_t)(seg0 >> 2) * (KA * 2) + (seg0 & 3) * 16;
  const size_t roff1 = (size_t)(seg1 >> 2) * (KA * 2) + (seg1 & 3) * 16;
  const int loff0 = (wid * 64) * 16;
  const int loff1 = (256 + wid * 64) * 16;

  f4_t acc[4][4] = {};

  auto stage = [&](int buf, int kt) {
    const int kb = kt * 64;
    GLDS16(gA + roff0 + kb, (char*)sA[buf] + loff0);
    GLDS16(gB + roff0 + kb, (char*)sB[buf] + loff0);
    GLDS16(gA + roff1 + kb, (char*)sA[buf] + loff1);
    GLDS16(gB + roff1 + kb, (char*)sB[buf] + loff1);
  };

  auto compute = [&](int buf) {
    bf8_t af[4], bfr[4];
    #pragma unroll
    for (int mi = 0; mi < 4; ++mi)
      af[mi] = *(const bf8_t*)(&sA[buf][(wm * 64 + mi * 16 + frow) * 32 + fk]);
    #pragma unroll
    for (int ni = 0; ni < 4; ++ni)
      bfr[ni] = *(const bf8_t*)(&sB[buf][(wn * 64 + ni * 16 + frow) * 32 + fk]);
    #pragma unroll
    for (int mi = 0; mi < 4; ++mi)
      #pragma unroll
      for (int ni = 0; ni < 4; ++ni)
        acc[mi][ni] = __builtin_amdgcn_mfma_f32_16x16x32_bf16(bfr[ni], af[mi], acc[mi][ni], 0, 0, 0);
  };

  constexpr int NKT = KA / 32;
  stage(0, 0);
  __syncthreads();                    // drains vmcnt: buf0 ready
  int cur = 0;
  for (int kt = 0; kt < NKT - 1; ++kt) {
    stage(cur ^ 1, kt + 1);           // issue next tile early
    compute(cur);                     // hide load latency under MFMA
    __syncthreads();                  // drain staged loads + guard buf reuse
    cur ^= 1;
  }
  compute(cur);                       // last tile, no prefetch

  const int cq = (lane >> 4) * 4;
  #pragma unroll
  for (int mi = 0; mi < 4; ++mi) {
    const int r = row0 + wm * 64 + mi * 16 + frow;
    unsigned short* crow = C + (size_t)r * KD;
    #pragma unroll
    for (int ni = 0; ni < 4; ++ni) {
      const int c = n0 + wn * 64 + ni * 16 + cq;
      if (c < KD) {  // wave-uniform per fragment
        f4_t v = acc[mi][ni];
        const f4_t bb = *(const f4_t*)(bias + c);
        float v0 = fmaxf(v[0] + bb[0], 0.f);
        float v1 = fmaxf(v[1] + bb[1], 0.f);
        float v2 = fmaxf(v[2] + bb[2], 0.f);
        float v3 = fmaxf(v[3] + bb[3], 0.f);
        uint2 pk;
        pk.x = (unsigned int)f2bf(v0) | ((unsigned int)f2bf(v1) << 16);
        pk.y = (unsigned int)f2bf(v2) | ((unsigned int)f2bf(v3) << 16);
        *(uint2*)(crow + c) = pk;
      }
    }
  }
}

// ---------------- final layer: out = A @ W3 + b3 (N=16 padded, write 12 cols f32) ----------
__global__ __launch_bounds__(256) void gemm_out(
    const unsigned short* __restrict__ A, const unsigned short* __restrict__ WT3,
    const float* __restrict__ b3, float* __restrict__ out) {
  __shared__ unsigned short sA[128 * 32];
  __shared__ unsigned short sB[16 * 32];
  const int tid = threadIdx.x, lane = tid & 63, wid = tid >> 6;
  const int row0 = blockIdx.x * 128;
  const char* gA = (const char*)A + (size_t)row0 * (KD * 2);
  const char* gB = (const char*)WT3;
  const int frow = lane & 15, fk = (lane >> 4) * 8;

  f4_t acc[2] = {};

  for (int kt = 0; kt < 25; ++kt) {
    const int kb = kt * 64;
    __syncthreads();
    #pragma unroll
    for (int L = 0; L < 2; ++L) {
      const int segb = L * 256 + wid * 64;
      const int seg = segb + lane;
      GLDS16(gA + (size_t)(seg >> 2) * (KD * 2) + kb + (seg & 3) * 16, (char*)sA + segb * 16);
    }
    if (wid == 0) {
      const int seg = lane;  // 16 rows x 32 K = 64 x 16B
      GLDS16(gB + (size_t)(seg >> 2) * (KD * 2) + kb + (seg & 3) * 16, (char*)sB);
    }
    __syncthreads();
    const bf8_t bf = *(const bf8_t*)(sB + frow * 32 + fk);
    #pragma unroll
    for (int mi = 0; mi < 2; ++mi) {
      const bf8_t af = *(const bf8_t*)(sA + (wid * 32 + mi * 16 + frow) * 32 + fk);
      acc[mi] = __builtin_amdgcn_mfma_f32_16x16x32_bf16(bf, af, acc[mi], 0, 0, 0);
    }
  }

  const int cg = (lane >> 4) * 4;
  #pragma unroll
  for (int mi = 0; mi < 2; ++mi) {
    const int r = row0 + wid * 32 + mi * 16 + frow;
    if (r < NROWS && cg < 12) {
      f4_t v = acc[mi];
      const f4_t bb = *(const f4_t*)(b3 + cg);  // cg in {0,4,8}: reads b3[0..11]
      v += bb;
      *(f4_t*)(out + (size_t)r * 12 + cg) = v;
    }
  }
}

// ---------------- host ----------------
extern "C" void kernel_launch(void* const* d_in, const int* in_sizes, int n_in,
                              void* d_out, int out_size, void* d_ws, size_t ws_size,
                              hipStream_t stream) {
  const float* mixer    = (const float*)d_in[0];
  const float* features = (const float*)d_in[1];
  const int*   sg_batch = (const int*)d_in[2];
  const int*   sg_map   = (const int*)d_in[3];
  const float* W0 = (const float*)d_in[4];  const float* b0 = (const float*)d_in[5];
  const float* W1 = (const float*)d_in[6];  const float* b1 = (const float*)d_in[7];
  const float* W2 = (const float*)d_in[8];  const float* b2 = (const float*)d_in[9];
  const float* W3 = (const float*)d_in[10]; const float* b3 = (const float*)d_in[11];
  float* out = (float*)d_out;

  char* wsp = (char*)d_ws;
  auto alloc = [&](size_t bytes) { char* p = wsp; wsp += (bytes + 255) & ~(size_t)255; return p; };
  unsigned short* h0  = (unsigned short*)alloc((size_t)MPAD * KD * 2);   // 64.1 MB
  unsigned short* h1  = (unsigned short*)alloc((size_t)MPAD * KD * 2);   // 64.1 MB
  unsigned short* Wt1 = (unsigned short*)alloc((size_t)NPW * KD * 2);
  unsigned short* Wt2 = (unsigned short*)alloc((size_t)NPW * KD * 2);
  unsigned short* Wt3 = (unsigned short*)alloc((size_t)16 * KD * 2);
  unsigned short* WTB = (unsigned short*)alloc((size_t)NPW * KA0 * 2);
  float* bp0   = (float*)alloc(KD * 4);
  float* bp1   = (float*)alloc(KD * 4);
  float* bp2   = (float*)alloc(KD * 4);
  float* fW0   = (float*)alloc((size_t)128 * KD * 4);
  int* counts  = (int*)alloc(NSEG * 4);
  // Cff (20.5 MB f32) and Abuf (12.8 MB bf16) alias h1's space: both are dead
  // before the first write to h1 (layer-1 GEMM output).
  float* Cff = (float*)h1;
  unsigned short* Abuf = (unsigned short*)((char*)h1 + ((size_t)MPAD * 128 * 4 + 255 & ~(size_t)255));

  // segment counts
  k_zero<<<(NSEG + 255) / 256, 256, 0, stream>>>(counts);
  k_count<<<(EN + 255) / 256, 256, 0, stream>>>(sg_map, counts);

  // Cf coefficient matrix
  k_zerof<<<(MPAD * 128 + 255) / 256, 256, 0, stream>>>(Cff, MPAD * 128);
  k_scatterCf<<<(EN + 255) / 256, 256, 0, stream>>>(sg_map, sg_batch, Cff);

  // weight prep
  k_flatW0<<<dim3(13, 16), 256, 0, stream>>>(mixer, W0, fW0);
  k_tpad<<<(NPW * KD + 255) / 256, 256, 0, stream>>>(W1, Wt1, 780, 780, NPW * KD);
  k_tpad<<<(NPW * KD + 255) / 256, 256, 0, stream>>>(W2, Wt2, 780, 780, NPW * KD);
  k_tpad<<<(16 * KD + 255) / 256, 256, 0, stream>>>(W3, Wt3, 12, 12, 16 * KD);
  k_padbias3<<<(3 * KD + 255) / 256, 256, 0, stream>>>(b0, b1, b2, bp0, bp1, bp2);
  k_buildB<<<(NPW * KA0 + 255) / 256, 256, 0, stream>>>(W0, fW0, WTB);

  // layer-0 operand A = [features | Cf | 0]
  k_buildA<<<(MPAD * KA0 + 255) / 256, 256, 0, stream>>>(features, counts, Cff, Abuf);

  // layer 0 as GEMM (K=160) -> h0
  gemm_relu<KA0><<<(MPAD / 128) * NT, 256, 0, stream>>>(Abuf, WTB, bp0, h0);

  // layers 1,2 (dense bf16 MFMA, K=800) -> h1 -> h0
  gemm_relu<KD><<<(MPAD / 128) * NT, 256, 0, stream>>>(h0, Wt1, bp1, h1);
  gemm_relu<KD><<<(MPAD / 128) * NT, 256, 0, stream>>>(h1, Wt2, bp2, h0);

  // layer 3 -> out
  gemm_out<<<MPAD / 128, 256, 0, stream>>>(h0, Wt3, b3, out);
}

// Round 9
// 375.784 us; speedup vs baseline: 1.1299x; 1.1299x over previous
//
#include <hip/hip_runtime.h>

// Problem constants (fixed by setup_inputs)
#define BG    4        // num_graphs
#define TT    12       // timesteps
#define NN    10000    // nodes per graph
#define EN    200000   // membership entries
#define NSEG  40000    // n*B segments
#define NROWS 40000    // B*n output rows
#define MPAD  40064    // 313*128
#define KD    832      // padded in_dim (780 -> 832 = 13*64) ; also h* row stride
#define KA0   160      // padded K for layer0 GEMM: 12 features + 128 Cf + 20 zero
#define NPW   896      // padded N for weight tiles (7*128)
#define NT    7        // N-tiles per row panel (NPW/128)

typedef __attribute__((ext_vector_type(8))) short bf8_t;   // 8 bf16 (4 VGPR) MFMA A/B frag
typedef __attribute__((ext_vector_type(4))) float f4_t;    // 4 f32 MFMA C/D frag

__device__ __forceinline__ unsigned short f2bf(float x) {  // RNE f32->bf16
  unsigned int u = __float_as_uint(x);
  u += 0x7fffu + ((u >> 16) & 1u);
  return (unsigned short)(u >> 16);
}

#define GLDS16(src, dst) __builtin_amdgcn_global_load_lds( \
    (const __attribute__((address_space(1))) void*)(src),  \
    (__attribute__((address_space(3))) void*)(dst), 16, 0, 0)

// ---------------- prep ----------------
__global__ void k_zero(int* counts) {
  int i = blockIdx.x * 256 + threadIdx.x;
  if (i < NSEG) counts[i] = 0;
}

__global__ void k_count(const int* __restrict__ mapper, int* __restrict__ counts) {
  int e = blockIdx.x * 256 + threadIdx.x;
  if (e < EN) atomicAdd(&counts[mapper[e]], 1);
}

__global__ void k_zerof(float* __restrict__ p, int n) {
  int i = blockIdx.x * 256 + threadIdx.x;
  if (i < n) p[i] = 0.f;
}

// Cf scatter: entry e contributes 1 to Cff[r][batch[e]], r = output row of segment mapper[e]
__global__ void k_scatterCf(const int* __restrict__ mapper, const int* __restrict__ batch,
                            float* __restrict__ Cff) {
  int e = blockIdx.x * 256 + threadIdx.x;
  if (e < EN) {
    const int s = mapper[e];
    const int r = (s % BG) * NN + s / BG;   // inverse of s = (r%NN)*BG + r/NN
    atomicAdd(&Cff[(size_t)r * 128 + batch[e]], 1.0f);
  }
}

// A = [features(12) | Cf(128) | 0(20)] as bf16, [MPAD][KA0]
__global__ void k_buildA(const float* __restrict__ features, const int* __restrict__ counts,
                         const float* __restrict__ Cff, unsigned short* __restrict__ A) {
  int idx = blockIdx.x * 256 + threadIdx.x;
  if (idx >= MPAD * KA0) return;
  const int r = idx / KA0, c = idx - r * KA0;
  float v = 0.f;
  if (r < NROWS) {
    if (c < 12) {
      v = features[(size_t)r * TT + c];
    } else if (c < 140) {
      const int s = (r % NN) * BG + (r / NN);
      const int cnt = counts[s];
      const float inv = 1.f / (float)(cnt > 0 ? cnt : 1);
      v = Cff[(size_t)r * 128 + (c - 12)] * inv;
    }
  }
  A[idx] = f2bf(v);
}

// B^T for layer0 GEMM: WTB[n][k] = k<12 ? W0[k][n] : k<140 ? fW0[k-12][n] : 0; [NPW][KA0]
__global__ void k_buildB(const float* __restrict__ W0, const float* __restrict__ fW0,
                         unsigned short* __restrict__ WTB) {
  int idx = blockIdx.x * 256 + threadIdx.x;
  if (idx >= NPW * KA0) return;
  const int n = idx / KA0, k = idx - n * KA0;
  float v = 0.f;
  if (n < 780) {
    if (k < 12) v = W0[(size_t)k * 780 + n];
    else if (k < 140) v = fW0[(size_t)(k - 12) * KD + n];
  }
  WTB[idx] = f2bf(v);
}

// Wt[n][k] = W[k][n], zero-padded to [Nrows][KD] bf16. W is [780][ldw].
__global__ void k_tpad(const float* __restrict__ W, unsigned short* __restrict__ Wt,
                       int ldw, int nsrc, int total) {
  int idx = blockIdx.x * 256 + threadIdx.x;
  if (idx >= total) return;
  int n = idx / KD, k = idx % KD;
  float v = (n < nsrc && k < 780) ? W[k * ldw + n] : 0.f;
  Wt[idx] = f2bf(v);
}

// pad b0,b1,b2 -> bp0,bp1,bp2 (KD wide, zeros past 780)
__global__ void k_padbias3(const float* __restrict__ b0, const float* __restrict__ b1,
                           const float* __restrict__ b2, float* __restrict__ p0,
                           float* __restrict__ p1, float* __restrict__ p2) {
  int i = blockIdx.x * 256 + threadIdx.x;
  if (i >= 3 * KD) return;
  const int which = i / KD, c = i - which * KD;
  const float* src = which == 0 ? b0 : (which == 1 ? b1 : b2);
  float* dst = which == 0 ? p0 : (which == 1 ? p1 : p2);
  dst[c] = (c < 780) ? src[c] : 0.f;
}

// flatW0[j][c] = sum_k flat[j][k] * W0[12+k][c], j<128, c<780 (0 for 780<=c<832)
// flat[j][t*64+f] = mixer_x[j%4][t][j/4][f]
// Split-K f32: grid (13 c-tiles x 16 j-tiles), block 256 = 64 c-lanes x 4 k-splits.
__global__ __launch_bounds__(256) void k_flatW0(const float* __restrict__ mixer,
                                                const float* __restrict__ W0,
                                                float* __restrict__ fW0) {
  __shared__ float sA[8][768];       // 24 KB: 8 A-rows
  __shared__ float sRed[4][64][9];   // 9.2 KB, pad 9 -> conflict-free
  const int tid = threadIdx.x;
  const int c0 = blockIdx.x * 64, j0 = blockIdx.y * 8;
  for (int i = tid; i < 8 * 768; i += 256) {
    int jj = i / 768;
    int k = i - jj * 768;
    int j = j0 + jj;
    int tt = k >> 6, ff = k & 63;
    sA[jj][k] = mixer[(((j & 3) * TT + tt) * 32 + (j >> 2)) * 64 + ff];
  }
  __syncthreads();
  const int cc = tid & 63, ks = tid >> 6;
  const int c = c0 + cc;
  float acc[8] = {};
  if (c < 780) {
    const float* wp = W0 + (size_t)(12 + ks * 192) * 780 + c;
    #pragma unroll 4
    for (int k = ks * 192; k < ks * 192 + 192; ++k) {
      const float w = *wp; wp += 780;
      #pragma unroll
      for (int jj = 0; jj < 8; ++jj) acc[jj] = fmaf(sA[jj][k], w, acc[jj]);
    }
  }
  #pragma unroll
  for (int jj = 0; jj < 8; ++jj) sRed[ks][cc][jj] = acc[jj];
  __syncthreads();
  for (int o = tid; o < 512; o += 256) {
    const int oc = o & 63, jj = o >> 6;
    const int wc = c0 + oc;
    if (wc < KD) {
      float s = sRed[0][oc][jj] + sRed[1][oc][jj] + sRed[2][oc][jj] + sRed[3][oc][jj];
      fW0[(size_t)(j0 + jj) * KD + wc] = s;  // cols >=780 stayed 0
    }
  }
}

// ---------------- dense layers: C = relu(A @ W + b), bf16 MFMA ----------------
// A [MPAD][KA] bf16, WT [*][KA] bf16, C [MPAD][KD] bf16 (output stride always KD).
// 128x128 tile, 4 waves (2x2), global_load_lds w=16, XCD swizzle (R6).
// R8 post-mortem: explicit dbuf regressed (occupancy 18.5%, barrier still
// drains vmcnt). R9: revert to the R7 2-barrier structure, but BK 32->64
// (template) to HALVE the number of drain windows per block (25 -> 13).
// Bank conflicts rise (128B row stride) but are hidden under the stage
// stall at 2-phase (m252: conflict-fix is time-null here).
template<int KA, int BK>
__global__ __launch_bounds__(256) void gemm_relu(
    const unsigned short* __restrict__ A, const unsigned short* __restrict__ WT,
    const float* __restrict__ bias, unsigned short* __restrict__ C) {
  constexpr int SEGR = BK / 8;                 // 16B segments per row
  constexpr int NISS = (128 * SEGR) / 256;     // per-thread issues per operand
  __shared__ unsigned short sA[128 * BK];
  __shared__ unsigned short sB[128 * BK];
  const int tid = threadIdx.x, lane = tid & 63, wid = tid >> 6;
  const int wm = wid >> 1, wn = wid & 1;

  // bijective XCD swizzle (nwg = 313*NT = 2191)
  const int nwg = gridDim.x;
  const int q = nwg >> 3, r8 = nwg & 7;
  const int xcd = blockIdx.x & 7, bidx = blockIdx.x >> 3;
  const int linear = (xcd < r8 ? xcd * (q + 1) : r8 * (q + 1) + (xcd - r8) * q) + bidx;
  const int rowtile = linear / NT, ntile = linear - rowtile * NT;

  const int row0 = rowtile * 128, n0 = ntile * 128;
  const char* gA = (const char*)A + (size_t)row0 * (KA * 2);
  const char* gB = (const char*)WT + (size_t)n0 * (KA * 2);
  const int frow = lane & 15, fk = (lane >> 4) * 8;

  f4_t acc[4][4] = {};

  for (int kt = 0; kt < KA / BK; ++kt) {
    const int kb = kt * (BK * 2);  // byte offset of BK-element K chunk
    __syncthreads();
    #pragma unroll
    for (int L = 0; L < NISS; ++L) {
      const int seg = L * 256 + wid * 64 + lane;
      const int row = seg / SEGR, c16 = seg & (SEGR - 1);
      const size_t go = (size_t)row * (KA * 2) + kb + c16 * 16;
      GLDS16(gA + go, (char*)sA + seg * 16);
      GLDS16(gB + go, (char*)sB + seg * 16);
    }
    __syncthreads();
    #pragma unroll
    for (int kk = 0; kk < BK / 32; ++kk) {
      bf8_t af[4], bfr[4];
      #pragma unroll
      for (int mi = 0; mi < 4; ++mi)
        af[mi] = *(const bf8_t*)(&sA[(wm * 64 + mi * 16 + frow) * BK + kk * 32 + fk]);
      #pragma unroll
      for (int ni = 0; ni < 4; ++ni)
        bfr[ni] = *(const bf8_t*)(&sB[(wn * 64 + ni * 16 + frow) * BK + kk * 32 + fk]);
      #pragma unroll
      for (int mi = 0; mi < 4; ++mi)
        #pragma unroll
        for (int ni = 0; ni < 4; ++ni)
          acc[mi][ni] = __builtin_amdgcn_mfma_f32_16x16x32_bf16(bfr[ni], af[mi], acc[mi][ni], 0, 0, 0);
    }
  }

  const int cq = (lane >> 4) * 4;
  #pragma unroll
  for (int mi = 0; mi < 4; ++mi) {
    const int r = row0 + wm * 64 + mi * 16 + frow;
    unsigned short* crow = C + (size_t)r * KD;
    #pragma unroll
    for (int ni = 0; ni < 4; ++ni) {
      const int c = n0 + wn * 64 + ni * 16 + cq;
      if (c < KD) {  // wave-uniform per fragment
        f4_t v = acc[mi][ni];
        const f4_t bb = *(const f4_t*)(bias + c);
        float v0 = fmaxf(v[0] + bb[0], 0.f);
        float v1 = fmaxf(v[1] + bb[1], 0.f);
        float v2 = fmaxf(v[2] + bb[2], 0.f);
        float v3 = fmaxf(v[3] + bb[3], 0.f);
        uint2 pk;
        pk.x = (unsigned int)f2bf(v0) | ((unsigned int)f2bf(v1) << 16);
        pk.y = (unsigned int)f2bf(v2) | ((unsigned int)f2bf(v3) << 16);
        *(uint2*)(crow + c) = pk;
      }
    }
  }
}

// ---------------- final layer: out = A @ W3 + b3 (N=16 padded, write 12 cols f32) ----------
// BK=64, 13 K-steps (mirrors gemm_relu's R9 change).
__global__ __launch_bounds__(256) void gemm_out(
    const unsigned short* __restrict__ A, const unsigned short* __restrict__ WT3,
    const float* __restrict__ b3, float* __restrict__ out) {
  __shared__ unsigned short sA[128 * 64];
  __shared__ unsigned short sB[16 * 64];
  const int tid = threadIdx.x, lane = tid & 63, wid = tid >> 6;
  const int row0 = blockIdx.x * 128;
  const char* gA = (const char*)A + (size_t)row0 * (KD * 2);
  const char* gB = (const char*)WT3;
  const int frow = lane & 15, fk = (lane >> 4) * 8;

  f4_t acc[2] = {};

  for (int kt = 0; kt < KD / 64; ++kt) {
    const int kb = kt * 128;
    __syncthreads();
    #pragma unroll
    for (int L = 0; L < 4; ++L) {
      const int seg = L * 256 + wid * 64 + lane;     // 1024 segs: row=seg>>3
      const int row = seg >> 3, c16 = seg & 7;
      GLDS16(gA + (size_t)row * (KD * 2) + kb + c16 * 16, (char*)sA + seg * 16);
    }
    if (wid == 0) {
      #pragma unroll
      for (int L = 0; L < 2; ++L) {
        const int seg = L * 64 + lane;               // 128 segs: 16 rows x 8
        const int row = seg >> 3, c16 = seg & 7;
        GLDS16(gB + (size_t)row * (KD * 2) + kb + c16 * 16, (char*)sB + seg * 16);
      }
    }
    __syncthreads();
    #pragma unroll
    for (int kk = 0; kk < 2; ++kk) {
      const bf8_t bf = *(const bf8_t*)(&sB[frow * 64 + kk * 32 + fk]);
      #pragma unroll
      for (int mi = 0; mi < 2; ++mi) {
        const bf8_t af = *(const bf8_t*)(&sA[(wid * 32 + mi * 16 + frow) * 64 + kk * 32 + fk]);
        acc[mi] = __builtin_amdgcn_mfma_f32_16x16x32_bf16(bf, af, acc[mi], 0, 0, 0);
      }
    }
  }

  const int cg = (lane >> 4) * 4;
  #pragma unroll
  for (int mi = 0; mi < 2; ++mi) {
    const int r = row0 + wid * 32 + mi * 16 + frow;
    if (r < NROWS && cg < 12) {
      f4_t v = acc[mi];
      const f4_t bb = *(const f4_t*)(b3 + cg);  // cg in {0,4,8}: reads b3[0..11]
      v += bb;
      *(f4_t*)(out + (size_t)r * 12 + cg) = v;
    }
  }
}

// ---------------- host ----------------
extern "C" void kernel_launch(void* const* d_in, const int* in_sizes, int n_in,
                              void* d_out, int out_size, void* d_ws, size_t ws_size,
                              hipStream_t stream) {
  const float* mixer    = (const float*)d_in[0];
  const float* features = (const float*)d_in[1];
  const int*   sg_batch = (const int*)d_in[2];
  const int*   sg_map   = (const int*)d_in[3];
  const float* W0 = (const float*)d_in[4];  const float* b0 = (const float*)d_in[5];
  const float* W1 = (const float*)d_in[6];  const float* b1 = (const float*)d_in[7];
  const float* W2 = (const float*)d_in[8];  const float* b2 = (const float*)d_in[9];
  const float* W3 = (const float*)d_in[10]; const float* b3 = (const float*)d_in[11];
  float* out = (float*)d_out;

  char* wsp = (char*)d_ws;
  auto alloc = [&](size_t bytes) { char* p = wsp; wsp += (bytes + 255) & ~(size_t)255; return p; };
  unsigned short* h0  = (unsigned short*)alloc((size_t)MPAD * KD * 2);   // 66.7 MB
  unsigned short* h1  = (unsigned short*)alloc((size_t)MPAD * KD * 2);   // 66.7 MB
  unsigned short* Wt1 = (unsigned short*)alloc((size_t)NPW * KD * 2);
  unsigned short* Wt2 = (unsigned short*)alloc((size_t)NPW * KD * 2);
  unsigned short* Wt3 = (unsigned short*)alloc((size_t)16 * KD * 2);
  unsigned short* WTB = (unsigned short*)alloc((size_t)NPW * KA0 * 2);
  float* bp0   = (float*)alloc(KD * 4);
  float* bp1   = (float*)alloc(KD * 4);
  float* bp2   = (float*)alloc(KD * 4);
  float* fW0   = (float*)alloc((size_t)128 * KD * 4);
  int* counts  = (int*)alloc(NSEG * 4);
  // Cff (20.5 MB f32) and Abuf (12.8 MB bf16) alias h1's space: both are dead
  // before the first write to h1 (layer-1 GEMM output).
  float* Cff = (float*)h1;
  unsigned short* Abuf = (unsigned short*)((char*)h1 + ((size_t)MPAD * 128 * 4 + 255 & ~(size_t)255));

  // segment counts
  k_zero<<<(NSEG + 255) / 256, 256, 0, stream>>>(counts);
  k_count<<<(EN + 255) / 256, 256, 0, stream>>>(sg_map, counts);

  // Cf coefficient matrix
  k_zerof<<<(MPAD * 128 + 255) / 256, 256, 0, stream>>>(Cff, MPAD * 128);
  k_scatterCf<<<(EN + 255) / 256, 256, 0, stream>>>(sg_map, sg_batch, Cff);

  // weight prep
  k_flatW0<<<dim3(13, 16), 256, 0, stream>>>(mixer, W0, fW0);
  k_tpad<<<(NPW * KD + 255) / 256, 256, 0, stream>>>(W1, Wt1, 780, 780, NPW * KD);
  k_tpad<<<(NPW * KD + 255) / 256, 256, 0, stream>>>(W2, Wt2, 780, 780, NPW * KD);
  k_tpad<<<(16 * KD + 255) / 256, 256, 0, stream>>>(W3, Wt3, 12, 12, 16 * KD);
  k_padbias3<<<(3 * KD + 255) / 256, 256, 0, stream>>>(b0, b1, b2, bp0, bp1, bp2);
  k_buildB<<<(NPW * KA0 + 255) / 256, 256, 0, stream>>>(W0, fW0, WTB);

  // layer-0 operand A = [features | Cf | 0]
  k_buildA<<<(MPAD * KA0 + 255) / 256, 256, 0, stream>>>(features, counts, Cff, Abuf);

  // layer 0 as GEMM (K=160, BK=32) -> h0
  gemm_relu<KA0, 32><<<(MPAD / 128) * NT, 256, 0, stream>>>(Abuf, WTB, bp0, h0);

  // layers 1,2 (dense bf16 MFMA, K=832, BK=64) -> h1 -> h0
  gemm_relu<KD, 64><<<(MPAD / 128) * NT, 256, 0, stream>>>(h0, Wt1, bp1, h1);
  gemm_relu<KD, 64><<<(MPAD / 128) * NT, 256, 0, stream>>>(h1, Wt2, bp2, h0);

  // layer 3 -> out
  gemm_out<<<MPAD / 128, 256, 0, stream>>>(h0, Wt3, b3, out);
}

// Round 10
// 359.906 us; speedup vs baseline: 1.1797x; 1.0441x over previous
//
#include <hip/hip_runtime.h>

// Problem constants (fixed by setup_inputs)
#define BG    4        // num_graphs
#define TT    12       // timesteps
#define NN    10000    // nodes per graph
#define EN    200000   // membership entries
#define NSEG  40000    // n*B segments
#define NROWS 40000    // B*n output rows
#define MPAD  40064    // 313*128
#define KD    832      // padded in_dim (780 -> 832 = 13*64) ; also h* row stride
#define KA0   160      // padded K for layer0 GEMM: 12 features + 128 Cf + 20 zero
#define NPW   896      // padded N for weight tiles (7*128)
#define NT    7        // N-tiles per row panel (NPW/128)

typedef __attribute__((ext_vector_type(8))) short bf8_t;   // 8 bf16 (4 VGPR) MFMA A/B frag
typedef __attribute__((ext_vector_type(4))) float f4_t;    // 4 f32 MFMA C/D frag

__device__ __forceinline__ unsigned short f2bf(float x) {  // RNE f32->bf16
  unsigned int u = __float_as_uint(x);
  u += 0x7fffu + ((u >> 16) & 1u);
  return (unsigned short)(u >> 16);
}

#define GLDS16(src, dst) __builtin_amdgcn_global_load_lds( \
    (const __attribute__((address_space(1))) void*)(src),  \
    (__attribute__((address_space(3))) void*)(dst), 16, 0, 0)

#define LKW0 asm volatile("s_waitcnt lgkmcnt(0)" ::: "memory")
#define VMW0 asm volatile("s_waitcnt vmcnt(0)" ::: "memory")

// ---------------- prep ----------------
__global__ void k_zero(int* counts) {
  int i = blockIdx.x * 256 + threadIdx.x;
  if (i < NSEG) counts[i] = 0;
}

__global__ void k_count(const int* __restrict__ mapper, int* __restrict__ counts) {
  int e = blockIdx.x * 256 + threadIdx.x;
  if (e < EN) atomicAdd(&counts[mapper[e]], 1);
}

__global__ void k_zerof(float* __restrict__ p, int n) {
  int i = blockIdx.x * 256 + threadIdx.x;
  if (i < n) p[i] = 0.f;
}

// Cf scatter: entry e contributes 1 to Cff[r][batch[e]], r = output row of segment mapper[e]
__global__ void k_scatterCf(const int* __restrict__ mapper, const int* __restrict__ batch,
                            float* __restrict__ Cff) {
  int e = blockIdx.x * 256 + threadIdx.x;
  if (e < EN) {
    const int s = mapper[e];
    const int r = (s % BG) * NN + s / BG;   // inverse of s = (r%NN)*BG + r/NN
    atomicAdd(&Cff[(size_t)r * 128 + batch[e]], 1.0f);
  }
}

// A = [features(12) | Cf(128) | 0(20)] as bf16, [MPAD][KA0]
__global__ void k_buildA(const float* __restrict__ features, const int* __restrict__ counts,
                         const float* __restrict__ Cff, unsigned short* __restrict__ A) {
  int idx = blockIdx.x * 256 + threadIdx.x;
  if (idx >= MPAD * KA0) return;
  const int r = idx / KA0, c = idx - r * KA0;
  float v = 0.f;
  if (r < NROWS) {
    if (c < 12) {
      v = features[(size_t)r * TT + c];
    } else if (c < 140) {
      const int s = (r % NN) * BG + (r / NN);
      const int cnt = counts[s];
      const float inv = 1.f / (float)(cnt > 0 ? cnt : 1);
      v = Cff[(size_t)r * 128 + (c - 12)] * inv;
    }
  }
  A[idx] = f2bf(v);
}

// B^T for layer0 GEMM: WTB[n][k] = k<12 ? W0[k][n] : k<140 ? fW0[k-12][n] : 0; [NPW][KA0]
__global__ void k_buildB(const float* __restrict__ W0, const float* __restrict__ fW0,
                         unsigned short* __restrict__ WTB) {
  int idx = blockIdx.x * 256 + threadIdx.x;
  if (idx >= NPW * KA0) return;
  const int n = idx / KA0, k = idx - n * KA0;
  float v = 0.f;
  if (n < 780) {
    if (k < 12) v = W0[(size_t)k * 780 + n];
    else if (k < 140) v = fW0[(size_t)(k - 12) * KD + n];
  }
  WTB[idx] = f2bf(v);
}

// Wt[n][k] = W[k][n], zero-padded to [Nrows][KD] bf16. W is [780][ldw].
__global__ void k_tpad(const float* __restrict__ W, unsigned short* __restrict__ Wt,
                       int ldw, int nsrc, int total) {
  int idx = blockIdx.x * 256 + threadIdx.x;
  if (idx >= total) return;
  int n = idx / KD, k = idx % KD;
  float v = (n < nsrc && k < 780) ? W[k * ldw + n] : 0.f;
  Wt[idx] = f2bf(v);
}

// pad b0,b1,b2 -> bp0,bp1,bp2 (KD wide, zeros past 780)
__global__ void k_padbias3(const float* __restrict__ b0, const float* __restrict__ b1,
                           const float* __restrict__ b2, float* __restrict__ p0,
                           float* __restrict__ p1, float* __restrict__ p2) {
  int i = blockIdx.x * 256 + threadIdx.x;
  if (i >= 3 * KD) return;
  const int which = i / KD, c = i - which * KD;
  const float* src = which == 0 ? b0 : (which == 1 ? b1 : b2);
  float* dst = which == 0 ? p0 : (which == 1 ? p1 : p2);
  dst[c] = (c < 780) ? src[c] : 0.f;
}

// flatW0[j][c] = sum_k flat[j][k] * W0[12+k][c], j<128, c<780 (0 for 780<=c<832)
// flat[j][t*64+f] = mixer_x[j%4][t][j/4][f]
// Split-K f32: grid (13 c-tiles x 16 j-tiles), block 256 = 64 c-lanes x 4 k-splits.
__global__ __launch_bounds__(256) void k_flatW0(const float* __restrict__ mixer,
                                                const float* __restrict__ W0,
                                                float* __restrict__ fW0) {
  __shared__ float sA[8][768];       // 24 KB: 8 A-rows
  __shared__ float sRed[4][64][9];   // 9.2 KB, pad 9 -> conflict-free
  const int tid = threadIdx.x;
  const int c0 = blockIdx.x * 64, j0 = blockIdx.y * 8;
  for (int i = tid; i < 8 * 768; i += 256) {
    int jj = i / 768;
    int k = i - jj * 768;
    int j = j0 + jj;
    int tt = k >> 6, ff = k & 63;
    sA[jj][k] = mixer[(((j & 3) * TT + tt) * 32 + (j >> 2)) * 64 + ff];
  }
  __syncthreads();
  const int cc = tid & 63, ks = tid >> 6;
  const int c = c0 + cc;
  float acc[8] = {};
  if (c < 780) {
    const float* wp = W0 + (size_t)(12 + ks * 192) * 780 + c;
    #pragma unroll 4
    for (int k = ks * 192; k < ks * 192 + 192; ++k) {
      const float w = *wp; wp += 780;
      #pragma unroll
      for (int jj = 0; jj < 8; ++jj) acc[jj] = fmaf(sA[jj][k], w, acc[jj]);
    }
  }
  #pragma unroll
  for (int jj = 0; jj < 8; ++jj) sRed[ks][cc][jj] = acc[jj];
  __syncthreads();
  for (int o = tid; o < 512; o += 256) {
    const int oc = o & 63, jj = o >> 6;
    const int wc = c0 + oc;
    if (wc < KD) {
      float s = sRed[0][oc][jj] + sRed[1][oc][jj] + sRed[2][oc][jj] + sRed[3][oc][jj];
      fW0[(size_t)(j0 + jj) * KD + wc] = s;  // cols >=780 stayed 0
    }
  }
}

// ---------------- dense layers: C = relu(A @ W + b), bf16 MFMA ----------------
// A [MPAD][KA] bf16, WT [*][KA] bf16, C [MPAD][KD] bf16 (output stride always KD).
// 128x128 tile, 4 waves (2x2), global_load_lds w=16, XCD swizzle (R6).
// R10: counted-vmcnt 2-deep pipeline (T3/T4 mechanism) + T2 both-sides XOR
// swizzle. Per tile t: pre-read ALL frags to regs -> lgkmcnt(0)+barrier (buf
// dead) -> STAGE(t+2) into freed buf -> MFMA (setprio) -> vmcnt(2*NISS)
// (waits tile t+1 only; t+2 stays in flight ~2 compute phases) -> barrier.
// Swizzle (rule #21): LDS dest linear; SOURCE 16B-chunk c16^(row&MASK);
// read applies same XOR -> involution. Kills the 16-way row-stride conflict.
template<int KA, int BK>
__global__ __launch_bounds__(256) void gemm_relu(
    const unsigned short* __restrict__ A, const unsigned short* __restrict__ WT,
    const float* __restrict__ bias, unsigned short* __restrict__ C) {
  constexpr int SEGR = BK / 8;                 // 16B chunks per row
  constexpr int MASK = SEGR - 1;
  constexpr int NISS = (128 * SEGR) / 256;     // per-thread issues per operand
  constexpr int NKT  = KA / BK;
  constexpr int NKK  = BK / 32;
  __shared__ unsigned short sA[2][128 * BK];
  __shared__ unsigned short sB[2][128 * BK];
  const int tid = threadIdx.x, lane = tid & 63, wid = tid >> 6;
  const int wm = wid >> 1, wn = wid & 1;

  // bijective XCD swizzle (nwg = 313*NT = 2191)
  const int nwg = gridDim.x;
  const int q = nwg >> 3, r8 = nwg & 7;
  const int xcd = blockIdx.x & 7, bidx = blockIdx.x >> 3;
  const int linear = (xcd < r8 ? xcd * (q + 1) : r8 * (q + 1) + (xcd - r8) * q) + bidx;
  const int rowtile = linear / NT, ntile = linear - rowtile * NT;

  const int row0 = rowtile * 128, n0 = ntile * 128;
  const char* gA = (const char*)A + (size_t)row0 * (KA * 2);
  const char* gB = (const char*)WT + (size_t)n0 * (KA * 2);
  const int frow = lane & 15;

  // t-invariant swizzled frag offsets (element units), compile-time indexed
  int offA[NKK][4], offB[NKK][4];
  #pragma unroll
  for (int kk = 0; kk < NKK; ++kk) {
    const int c16r = kk * 4 + (lane >> 4);
    #pragma unroll
    for (int i = 0; i < 4; ++i) {
      const int ra = wm * 64 + i * 16 + frow;
      const int rb = wn * 64 + i * 16 + frow;
      offA[kk][i] = ra * BK + ((c16r ^ (ra & MASK)) * 8);
      offB[kk][i] = rb * BK + ((c16r ^ (rb & MASK)) * 8);
    }
  }

  auto stage = [&](int b, int kt) {
    const int kb = kt * (BK * 2);
    #pragma unroll
    for (int L = 0; L < NISS; ++L) {
      const int seg = L * 256 + wid * 64 + lane;
      const int row = seg / SEGR, c16 = seg & MASK;
      const int c16s = c16 ^ (row & MASK);                 // pre-swizzled source
      const size_t go = (size_t)row * (KA * 2) + kb + c16s * 16;
      GLDS16(gA + go, (char*)sA[b] + seg * 16);
      GLDS16(gB + go, (char*)sB[b] + seg * 16);
    }
  };

  f4_t acc[4][4] = {};

  // prologue: tiles 0,1 in flight; wait tile 0
  stage(0, 0);
  stage(1, 1);
  if constexpr (BK == 64) asm volatile("s_waitcnt vmcnt(8)" ::: "memory");
  else                    asm volatile("s_waitcnt vmcnt(4)" ::: "memory");
  __builtin_amdgcn_s_barrier();

  #pragma unroll
  for (int t = 0; t < NKT; ++t) {
    const int cur = t & 1;
    bf8_t af[NKK][4], bfv[NKK][4];
    #pragma unroll
    for (int kk = 0; kk < NKK; ++kk) {
      #pragma unroll
      for (int i = 0; i < 4; ++i) {
        af[kk][i]  = *(const bf8_t*)(&sA[cur][offA[kk][i]]);
        bfv[kk][i] = *(const bf8_t*)(&sB[cur][offB[kk][i]]);
      }
    }
    if (t < NKT - 1) {
      LKW0;                               // own frag reads done (regs hold tile t)
      __builtin_amdgcn_s_barrier();       // all waves done reading buf[cur]
      __builtin_amdgcn_sched_barrier(0);  // pin: no motion across the fence
      if (t + 2 < NKT) stage(cur, t + 2); // overwrite freed buf; stays in flight
    }
    __builtin_amdgcn_s_setprio(1);
    #pragma unroll
    for (int kk = 0; kk < NKK; ++kk)
      #pragma unroll
      for (int mi = 0; mi < 4; ++mi)
        #pragma unroll
        for (int ni = 0; ni < 4; ++ni)
          acc[mi][ni] = __builtin_amdgcn_mfma_f32_16x16x32_bf16(bfv[kk][ni], af[kk][mi], acc[mi][ni], 0, 0, 0);
    __builtin_amdgcn_s_setprio(0);
    if (t < NKT - 1) {
      if (t + 2 < NKT) {                  // wait tile t+1 only (t+2 in flight)
        if constexpr (BK == 64) asm volatile("s_waitcnt vmcnt(8)" ::: "memory");
        else                    asm volatile("s_waitcnt vmcnt(4)" ::: "memory");
      } else {
        VMW0;                             // last prefetch: full drain
      }
      __builtin_amdgcn_s_barrier();
    }
  }

  const int cq = (lane >> 4) * 4;
  #pragma unroll
  for (int mi = 0; mi < 4; ++mi) {
    const int r = row0 + wm * 64 + mi * 16 + frow;
    unsigned short* crow = C + (size_t)r * KD;
    #pragma unroll
    for (int ni = 0; ni < 4; ++ni) {
      const int c = n0 + wn * 64 + ni * 16 + cq;
      if (c < KD) {  // wave-uniform per fragment
        f4_t v = acc[mi][ni];
        const f4_t bb = *(const f4_t*)(bias + c);
        float v0 = fmaxf(v[0] + bb[0], 0.f);
        float v1 = fmaxf(v[1] + bb[1], 0.f);
        float v2 = fmaxf(v[2] + bb[2], 0.f);
        float v3 = fmaxf(v[3] + bb[3], 0.f);
        uint2 pk;
        pk.x = (unsigned int)f2bf(v0) | ((unsigned int)f2bf(v1) << 16);
        pk.y = (unsigned int)f2bf(v2) | ((unsigned int)f2bf(v3) << 16);
        *(uint2*)(crow + c) = pk;
      }
    }
  }
}

// ---------------- final layer: out = A @ W3 + b3 (N=16 padded, write 12 cols f32) ----------
// BK=64, 13 K-steps (unchanged R9 structure -- small kernel, risk contained).
__global__ __launch_bounds__(256) void gemm_out(
    const unsigned short* __restrict__ A, const unsigned short* __restrict__ WT3,
    const float* __restrict__ b3, float* __restrict__ out) {
  __shared__ unsigned short sA[128 * 64];
  __shared__ unsigned short sB[16 * 64];
  const int tid = threadIdx.x, lane = tid & 63, wid = tid >> 6;
  const int row0 = blockIdx.x * 128;
  const char* gA = (const char*)A + (size_t)row0 * (KD * 2);
  const char* gB = (const char*)WT3;
  const int frow = lane & 15, fk = (lane >> 4) * 8;

  f4_t acc[2] = {};

  for (int kt = 0; kt < KD / 64; ++kt) {
    const int kb = kt * 128;
    __syncthreads();
    #pragma unroll
    for (int L = 0; L < 4; ++L) {
      const int seg = L * 256 + wid * 64 + lane;     // 1024 segs: row=seg>>3
      const int row = seg >> 3, c16 = seg & 7;
      GLDS16(gA + (size_t)row * (KD * 2) + kb + c16 * 16, (char*)sA + seg * 16);
    }
    if (wid == 0) {
      #pragma unroll
      for (int L = 0; L < 2; ++L) {
        const int seg = L * 64 + lane;               // 128 segs: 16 rows x 8
        const int row = seg >> 3, c16 = seg & 7;
        GLDS16(gB + (size_t)row * (KD * 2) + kb + c16 * 16, (char*)sB + seg * 16);
      }
    }
    __syncthreads();
    #pragma unroll
    for (int kk = 0; kk < 2; ++kk) {
      const bf8_t bf = *(const bf8_t*)(&sB[frow * 64 + kk * 32 + fk]);
      #pragma unroll
      for (int mi = 0; mi < 2; ++mi) {
        const bf8_t af = *(const bf8_t*)(&sA[(wid * 32 + mi * 16 + frow) * 64 + kk * 32 + fk]);
        acc[mi] = __builtin_amdgcn_mfma_f32_16x16x32_bf16(bf, af, acc[mi], 0, 0, 0);
      }
    }
  }

  const int cg = (lane >> 4) * 4;
  #pragma unroll
  for (int mi = 0; mi < 2; ++mi) {
    const int r = row0 + wid * 32 + mi * 16 + frow;
    if (r < NROWS && cg < 12) {
      f4_t v = acc[mi];
      const f4_t bb = *(const f4_t*)(b3 + cg);  // cg in {0,4,8}: reads b3[0..11]
      v += bb;
      *(f4_t*)(out + (size_t)r * 12 + cg) = v;
    }
  }
}

// ---------------- host ----------------
extern "C" void kernel_launch(void* const* d_in, const int* in_sizes, int n_in,
                              void* d_out, int out_size, void* d_ws, size_t ws_size,
                              hipStream_t stream) {
  const float* mixer    = (const float*)d_in[0];
  const float* features = (const float*)d_in[1];
  const int*   sg_batch = (const int*)d_in[2];
  const int*   sg_map   = (const int*)d_in[3];
  const float* W0 = (const float*)d_in[4];  const float* b0 = (const float*)d_in[5];
  const float* W1 = (const float*)d_in[6];  const float* b1 = (const float*)d_in[7];
  const float* W2 = (const float*)d_in[8];  const float* b2 = (const float*)d_in[9];
  const float* W3 = (const float*)d_in[10]; const float* b3 = (const float*)d_in[11];
  float* out = (float*)d_out;

  char* wsp = (char*)d_ws;
  auto alloc = [&](size_t bytes) { char* p = wsp; wsp += (bytes + 255) & ~(size_t)255; return p; };
  unsigned short* h0  = (unsigned short*)alloc((size_t)MPAD * KD * 2);   // 66.7 MB
  unsigned short* h1  = (unsigned short*)alloc((size_t)MPAD * KD * 2);   // 66.7 MB
  unsigned short* Wt1 = (unsigned short*)alloc((size_t)NPW * KD * 2);
  unsigned short* Wt2 = (unsigned short*)alloc((size_t)NPW * KD * 2);
  unsigned short* Wt3 = (unsigned short*)alloc((size_t)16 * KD * 2);
  unsigned short* WTB = (unsigned short*)alloc((size_t)NPW * KA0 * 2);
  float* bp0   = (float*)alloc(KD * 4);
  float* bp1   = (float*)alloc(KD * 4);
  float* bp2   = (float*)alloc(KD * 4);
  float* fW0   = (float*)alloc((size_t)128 * KD * 4);
  int* counts  = (int*)alloc(NSEG * 4);
  // Cff (20.5 MB f32) and Abuf (12.8 MB bf16) alias h1's space: both are dead
  // before the first write to h1 (layer-1 GEMM output).
  float* Cff = (float*)h1;
  unsigned short* Abuf = (unsigned short*)((char*)h1 + ((size_t)MPAD * 128 * 4 + 255 & ~(size_t)255));

  // segment counts
  k_zero<<<(NSEG + 255) / 256, 256, 0, stream>>>(counts);
  k_count<<<(EN + 255) / 256, 256, 0, stream>>>(sg_map, counts);

  // Cf coefficient matrix
  k_zerof<<<(MPAD * 128 + 255) / 256, 256, 0, stream>>>(Cff, MPAD * 128);
  k_scatterCf<<<(EN + 255) / 256, 256, 0, stream>>>(sg_map, sg_batch, Cff);

  // weight prep
  k_flatW0<<<dim3(13, 16), 256, 0, stream>>>(mixer, W0, fW0);
  k_tpad<<<(NPW * KD + 255) / 256, 256, 0, stream>>>(W1, Wt1, 780, 780, NPW * KD);
  k_tpad<<<(NPW * KD + 255) / 256, 256, 0, stream>>>(W2, Wt2, 780, 780, NPW * KD);
  k_tpad<<<(16 * KD + 255) / 256, 256, 0, stream>>>(W3, Wt3, 12, 12, 16 * KD);
  k_padbias3<<<(3 * KD + 255) / 256, 256, 0, stream>>>(b0, b1, b2, bp0, bp1, bp2);
  k_buildB<<<(NPW * KA0 + 255) / 256, 256, 0, stream>>>(W0, fW0, WTB);

  // layer-0 operand A = [features | Cf | 0]
  k_buildA<<<(MPAD * KA0 + 255) / 256, 256, 0, stream>>>(features, counts, Cff, Abuf);

  // layer 0 as GEMM (K=160, BK=32) -> h0
  gemm_relu<KA0, 32><<<(MPAD / 128) * NT, 256, 0, stream>>>(Abuf, WTB, bp0, h0);

  // layers 1,2 (dense bf16 MFMA, K=832, BK=64) -> h1 -> h0
  gemm_relu<KD, 64><<<(MPAD / 128) * NT, 256, 0, stream>>>(h0, Wt1, bp1, h1);
  gemm_relu<KD, 64><<<(MPAD / 128) * NT, 256, 0, stream>>>(h1, Wt2, bp2, h0);

  // layer 3 -> out
  gemm_out<<<MPAD / 128, 256, 0, stream>>>(h0, Wt3, b3, out);
}

// Round 11
// 353.872 us; speedup vs baseline: 1.1998x; 1.0171x over previous
//
#include <hip/hip_runtime.h>

// Problem constants (fixed by setup_inputs)
#define BG    4        // num_graphs
#define TT    12       // timesteps
#define NN    10000    // nodes per graph
#define EN    200000   // membership entries
#define NSEG  40000    // n*B segments
#define NROWS 40000    // B*n output rows
#define MPAD  40064    // 313*128
#define KD    832      // padded in_dim (780 -> 832 = 13*64) ; also h* row stride
#define KA0   160      // padded K for layer0 GEMM: 12 features + 128 Cf + 20 zero
#define NPW   896      // padded N for weight tiles (7*128)
#define NT    7        // N-tiles per row panel (NPW/128)

typedef __attribute__((ext_vector_type(8))) short bf8_t;   // 8 bf16 (4 VGPR) MFMA A/B frag
typedef __attribute__((ext_vector_type(4))) float f4_t;    // 4 f32 MFMA C/D frag

__device__ __forceinline__ unsigned short f2bf(float x) {  // RNE f32->bf16
  unsigned int u = __float_as_uint(x);
  u += 0x7fffu + ((u >> 16) & 1u);
  return (unsigned short)(u >> 16);
}

#define GLDS16(src, dst) __builtin_amdgcn_global_load_lds( \
    (const __attribute__((address_space(1))) void*)(src),  \
    (__attribute__((address_space(3))) void*)(dst), 16, 0, 0)

#define LKW0 asm volatile("s_waitcnt lgkmcnt(0)" ::: "memory")
#define LKW8 asm volatile("s_waitcnt lgkmcnt(8)" ::: "memory")
#define VMW0 asm volatile("s_waitcnt vmcnt(0)" ::: "memory")
#define SBAR0 __builtin_amdgcn_sched_barrier(0)

// ---------------- prep ----------------
__global__ void k_zero(int* counts) {
  int i = blockIdx.x * 256 + threadIdx.x;
  if (i < NSEG) counts[i] = 0;
}

__global__ void k_count(const int* __restrict__ mapper, int* __restrict__ counts) {
  int e = blockIdx.x * 256 + threadIdx.x;
  if (e < EN) atomicAdd(&counts[mapper[e]], 1);
}

__global__ void k_zerof(float* __restrict__ p, int n) {
  int i = blockIdx.x * 256 + threadIdx.x;
  if (i < n) p[i] = 0.f;
}

// Cf scatter: entry e contributes 1 to Cff[r][batch[e]], r = output row of segment mapper[e]
__global__ void k_scatterCf(const int* __restrict__ mapper, const int* __restrict__ batch,
                            float* __restrict__ Cff) {
  int e = blockIdx.x * 256 + threadIdx.x;
  if (e < EN) {
    const int s = mapper[e];
    const int r = (s % BG) * NN + s / BG;   // inverse of s = (r%NN)*BG + r/NN
    atomicAdd(&Cff[(size_t)r * 128 + batch[e]], 1.0f);
  }
}

// A = [features(12) | Cf(128) | 0(20)] as bf16, [MPAD][KA0]
__global__ void k_buildA(const float* __restrict__ features, const int* __restrict__ counts,
                         const float* __restrict__ Cff, unsigned short* __restrict__ A) {
  int idx = blockIdx.x * 256 + threadIdx.x;
  if (idx >= MPAD * KA0) return;
  const int r = idx / KA0, c = idx - r * KA0;
  float v = 0.f;
  if (r < NROWS) {
    if (c < 12) {
      v = features[(size_t)r * TT + c];
    } else if (c < 140) {
      const int s = (r % NN) * BG + (r / NN);
      const int cnt = counts[s];
      const float inv = 1.f / (float)(cnt > 0 ? cnt : 1);
      v = Cff[(size_t)r * 128 + (c - 12)] * inv;
    }
  }
  A[idx] = f2bf(v);
}

// B^T for layer0 GEMM: WTB[n][k] = k<12 ? W0[k][n] : k<140 ? fW0[k-12][n] : 0; [NPW][KA0]
__global__ void k_buildB(const float* __restrict__ W0, const float* __restrict__ fW0,
                         unsigned short* __restrict__ WTB) {
  int idx = blockIdx.x * 256 + threadIdx.x;
  if (idx >= NPW * KA0) return;
  const int n = idx / KA0, k = idx - n * KA0;
  float v = 0.f;
  if (n < 780) {
    if (k < 12) v = W0[(size_t)k * 780 + n];
    else if (k < 140) v = fW0[(size_t)(k - 12) * KD + n];
  }
  WTB[idx] = f2bf(v);
}

// Wt[n][k] = W[k][n], zero-padded to [Nrows][KD] bf16. W is [780][ldw].
__global__ void k_tpad(const float* __restrict__ W, unsigned short* __restrict__ Wt,
                       int ldw, int nsrc, int total) {
  int idx = blockIdx.x * 256 + threadIdx.x;
  if (idx >= total) return;
  int n = idx / KD, k = idx % KD;
  float v = (n < nsrc && k < 780) ? W[k * ldw + n] : 0.f;
  Wt[idx] = f2bf(v);
}

// pad b0,b1,b2 -> bp0,bp1,bp2 (KD wide, zeros past 780)
__global__ void k_padbias3(const float* __restrict__ b0, const float* __restrict__ b1,
                           const float* __restrict__ b2, float* __restrict__ p0,
                           float* __restrict__ p1, float* __restrict__ p2) {
  int i = blockIdx.x * 256 + threadIdx.x;
  if (i >= 3 * KD) return;
  const int which = i / KD, c = i - which * KD;
  const float* src = which == 0 ? b0 : (which == 1 ? b1 : b2);
  float* dst = which == 0 ? p0 : (which == 1 ? p1 : p2);
  dst[c] = (c < 780) ? src[c] : 0.f;
}

// flatW0[j][c] = sum_k flat[j][k] * W0[12+k][c], j<128, c<780 (0 for 780<=c<832)
// flat[j][t*64+f] = mixer_x[j%4][t][j/4][f]
// Split-K f32: grid (13 c-tiles x 16 j-tiles), block 256 = 64 c-lanes x 4 k-splits.
__global__ __launch_bounds__(256) void k_flatW0(const float* __restrict__ mixer,
                                                const float* __restrict__ W0,
                                                float* __restrict__ fW0) {
  __shared__ float sA[8][768];       // 24 KB: 8 A-rows
  __shared__ float sRed[4][64][9];   // 9.2 KB, pad 9 -> conflict-free
  const int tid = threadIdx.x;
  const int c0 = blockIdx.x * 64, j0 = blockIdx.y * 8;
  for (int i = tid; i < 8 * 768; i += 256) {
    int jj = i / 768;
    int k = i - jj * 768;
    int j = j0 + jj;
    int tt = k >> 6, ff = k & 63;
    sA[jj][k] = mixer[(((j & 3) * TT + tt) * 32 + (j >> 2)) * 64 + ff];
  }
  __syncthreads();
  const int cc = tid & 63, ks = tid >> 6;
  const int c = c0 + cc;
  float acc[8] = {};
  if (c < 780) {
    const float* wp = W0 + (size_t)(12 + ks * 192) * 780 + c;
    #pragma unroll 4
    for (int k = ks * 192; k < ks * 192 + 192; ++k) {
      const float w = *wp; wp += 780;
      #pragma unroll
      for (int jj = 0; jj < 8; ++jj) acc[jj] = fmaf(sA[jj][k], w, acc[jj]);
    }
  }
  #pragma unroll
  for (int jj = 0; jj < 8; ++jj) sRed[ks][cc][jj] = acc[jj];
  __syncthreads();
  for (int o = tid; o < 512; o += 256) {
    const int oc = o & 63, jj = o >> 6;
    const int wc = c0 + oc;
    if (wc < KD) {
      float s = sRed[0][oc][jj] + sRed[1][oc][jj] + sRed[2][oc][jj] + sRed[3][oc][jj];
      fW0[(size_t)(j0 + jj) * KD + wc] = s;  // cols >=780 stayed 0
    }
  }
}

// ---------------- dense layers: C = relu(A @ W + b), bf16 MFMA ----------------
// A [MPAD][KA] bf16, WT [*][KA] bf16, C [MPAD][KD] bf16 (output stride always KD).
// 128x128 tile, 4 waves (2x2), global_load_lds w=16, XCD swizzle (R6).
// R10: counted-vmcnt 2-deep pipeline + T2 both-sides XOR swizzle (conflicts 0).
// R11: intra-iteration kk-split — issue kk0+kk1 frag reads, lgkmcnt(8) waits
// kk0 only, MFMA(kk0) hides kk1's read latency; lgkmcnt(0)+barrier then frees
// the buffer for STAGE(t+2); MFMA(kk1) follows. Each counted lgkmcnt is
// followed by sched_barrier(0) (rule #18: hipcc hoists reg-only MFMA past
// inline-asm waits otherwise).
template<int KA, int BK>
__global__ __launch_bounds__(256) void gemm_relu(
    const unsigned short* __restrict__ A, const unsigned short* __restrict__ WT,
    const float* __restrict__ bias, unsigned short* __restrict__ C) {
  constexpr int SEGR = BK / 8;                 // 16B chunks per row
  constexpr int MASK = SEGR - 1;
  constexpr int NISS = (128 * SEGR) / 256;     // per-thread issues per operand
  constexpr int NKT  = KA / BK;
  constexpr int NKK  = BK / 32;
  __shared__ unsigned short sA[2][128 * BK];
  __shared__ unsigned short sB[2][128 * BK];
  const int tid = threadIdx.x, lane = tid & 63, wid = tid >> 6;
  const int wm = wid >> 1, wn = wid & 1;

  // bijective XCD swizzle (nwg = 313*NT = 2191)
  const int nwg = gridDim.x;
  const int q = nwg >> 3, r8 = nwg & 7;
  const int xcd = blockIdx.x & 7, bidx = blockIdx.x >> 3;
  const int linear = (xcd < r8 ? xcd * (q + 1) : r8 * (q + 1) + (xcd - r8) * q) + bidx;
  const int rowtile = linear / NT, ntile = linear - rowtile * NT;

  const int row0 = rowtile * 128, n0 = ntile * 128;
  const char* gA = (const char*)A + (size_t)row0 * (KA * 2);
  const char* gB = (const char*)WT + (size_t)n0 * (KA * 2);
  const int frow = lane & 15;

  // t-invariant swizzled frag offsets (element units), compile-time indexed
  int offA[NKK][4], offB[NKK][4];
  #pragma unroll
  for (int kk = 0; kk < NKK; ++kk) {
    const int c16r = kk * 4 + (lane >> 4);
    #pragma unroll
    for (int i = 0; i < 4; ++i) {
      const int ra = wm * 64 + i * 16 + frow;
      const int rb = wn * 64 + i * 16 + frow;
      offA[kk][i] = ra * BK + ((c16r ^ (ra & MASK)) * 8);
      offB[kk][i] = rb * BK + ((c16r ^ (rb & MASK)) * 8);
    }
  }

  auto stage = [&](int b, int kt) {
    const int kb = kt * (BK * 2);
    #pragma unroll
    for (int L = 0; L < NISS; ++L) {
      const int seg = L * 256 + wid * 64 + lane;
      const int row = seg / SEGR, c16 = seg & MASK;
      const int c16s = c16 ^ (row & MASK);                 // pre-swizzled source
      const size_t go = (size_t)row * (KA * 2) + kb + c16s * 16;
      GLDS16(gA + go, (char*)sA[b] + seg * 16);
      GLDS16(gB + go, (char*)sB[b] + seg * 16);
    }
  };

  f4_t acc[4][4] = {};

  // prologue: tiles 0,1 in flight; wait tile 0
  stage(0, 0);
  stage(1, 1);
  if constexpr (BK == 64) asm volatile("s_waitcnt vmcnt(8)" ::: "memory");
  else                    asm volatile("s_waitcnt vmcnt(4)" ::: "memory");
  __builtin_amdgcn_s_barrier();

  #pragma unroll
  for (int t = 0; t < NKT; ++t) {
    const int cur = t & 1;
    if constexpr (NKK == 2) {
      bf8_t af0[4], bf0[4], af1[4], bf1[4];
      #pragma unroll
      for (int i = 0; i < 4; ++i) {           // kk=0 reads first
        af0[i] = *(const bf8_t*)(&sA[cur][offA[0][i]]);
        bf0[i] = *(const bf8_t*)(&sB[cur][offB[0][i]]);
      }
      SBAR0;                                  // pin issue order kk0 before kk1
      #pragma unroll
      for (int i = 0; i < 4; ++i) {           // kk=1 reads
        af1[i] = *(const bf8_t*)(&sA[cur][offA[1][i]]);
        bf1[i] = *(const bf8_t*)(&sB[cur][offB[1][i]]);
      }
      LKW8;                                   // kk0 landed; kk1 in flight
      SBAR0;
      __builtin_amdgcn_s_setprio(1);
      #pragma unroll
      for (int mi = 0; mi < 4; ++mi)
        #pragma unroll
        for (int ni = 0; ni < 4; ++ni)
          acc[mi][ni] = __builtin_amdgcn_mfma_f32_16x16x32_bf16(bf0[ni], af0[mi], acc[mi][ni], 0, 0, 0);
      __builtin_amdgcn_s_setprio(0);
      LKW0;                                   // kk1 landed (hidden under kk0 MFMA)
      SBAR0;
      if (t < NKT - 1) {
        __builtin_amdgcn_s_barrier();         // all waves done reading buf[cur]
        SBAR0;
        if (t + 2 < NKT) stage(cur, t + 2);   // overwrite freed buf
      }
      __builtin_amdgcn_s_setprio(1);
      #pragma unroll
      for (int mi = 0; mi < 4; ++mi)
        #pragma unroll
        for (int ni = 0; ni < 4; ++ni)
          acc[mi][ni] = __builtin_amdgcn_mfma_f32_16x16x32_bf16(bf1[ni], af1[mi], acc[mi][ni], 0, 0, 0);
      __builtin_amdgcn_s_setprio(0);
    } else {
      bf8_t af[4], bfv[4];
      #pragma unroll
      for (int i = 0; i < 4; ++i) {
        af[i]  = *(const bf8_t*)(&sA[cur][offA[0][i]]);
        bfv[i] = *(const bf8_t*)(&sB[cur][offB[0][i]]);
      }
      if (t < NKT - 1) {
        LKW0;
        __builtin_amdgcn_s_barrier();
        SBAR0;
        if (t + 2 < NKT) stage(cur, t + 2);
      } else {
        LKW0;
        SBAR0;
      }
      __builtin_amdgcn_s_setprio(1);
      #pragma unroll
      for (int mi = 0; mi < 4; ++mi)
        #pragma unroll
        for (int ni = 0; ni < 4; ++ni)
          acc[mi][ni] = __builtin_amdgcn_mfma_f32_16x16x32_bf16(bfv[ni], af[mi], acc[mi][ni], 0, 0, 0);
      __builtin_amdgcn_s_setprio(0);
    }
    if (t < NKT - 1) {
      if (t + 2 < NKT) {                      // wait tile t+1 only (t+2 in flight)
        if constexpr (BK == 64) asm volatile("s_waitcnt vmcnt(8)" ::: "memory");
        else                    asm volatile("s_waitcnt vmcnt(4)" ::: "memory");
      } else {
        VMW0;                                 // last prefetch: full drain
      }
      __builtin_amdgcn_s_barrier();
    }
  }

  const int cq = (lane >> 4) * 4;
  #pragma unroll
  for (int mi = 0; mi < 4; ++mi) {
    const int r = row0 + wm * 64 + mi * 16 + frow;
    unsigned short* crow = C + (size_t)r * KD;
    #pragma unroll
    for (int ni = 0; ni < 4; ++ni) {
      const int c = n0 + wn * 64 + ni * 16 + cq;
      if (c < KD) {  // wave-uniform per fragment
        f4_t v = acc[mi][ni];
        const f4_t bb = *(const f4_t*)(bias + c);
        float v0 = fmaxf(v[0] + bb[0], 0.f);
        float v1 = fmaxf(v[1] + bb[1], 0.f);
        float v2 = fmaxf(v[2] + bb[2], 0.f);
        float v3 = fmaxf(v[3] + bb[3], 0.f);
        uint2 pk;
        pk.x = (unsigned int)f2bf(v0) | ((unsigned int)f2bf(v1) << 16);
        pk.y = (unsigned int)f2bf(v2) | ((unsigned int)f2bf(v3) << 16);
        *(uint2*)(crow + c) = pk;
      }
    }
  }
}

// ---------------- final layer: out = A @ W3 + b3 (N=16 padded, write 12 cols f32) ----------
// BK=64, 13 K-steps (unchanged R9 structure -- small kernel, risk contained).
__global__ __launch_bounds__(256) void gemm_out(
    const unsigned short* __restrict__ A, const unsigned short* __restrict__ WT3,
    const float* __restrict__ b3, float* __restrict__ out) {
  __shared__ unsigned short sA[128 * 64];
  __shared__ unsigned short sB[16 * 64];
  const int tid = threadIdx.x, lane = tid & 63, wid = tid >> 6;
  const int row0 = blockIdx.x * 128;
  const char* gA = (const char*)A + (size_t)row0 * (KD * 2);
  const char* gB = (const char*)WT3;
  const int frow = lane & 15, fk = (lane >> 4) * 8;

  f4_t acc[2] = {};

  for (int kt = 0; kt < KD / 64; ++kt) {
    const int kb = kt * 128;
    __syncthreads();
    #pragma unroll
    for (int L = 0; L < 4; ++L) {
      const int seg = L * 256 + wid * 64 + lane;     // 1024 segs: row=seg>>3
      const int row = seg >> 3, c16 = seg & 7;
      GLDS16(gA + (size_t)row * (KD * 2) + kb + c16 * 16, (char*)sA + seg * 16);
    }
    if (wid == 0) {
      #pragma unroll
      for (int L = 0; L < 2; ++L) {
        const int seg = L * 64 + lane;               // 128 segs: 16 rows x 8
        const int row = seg >> 3, c16 = seg & 7;
        GLDS16(gB + (size_t)row * (KD * 2) + kb + c16 * 16, (char*)sB + seg * 16);
      }
    }
    __syncthreads();
    #pragma unroll
    for (int kk = 0; kk < 2; ++kk) {
      const bf8_t bf = *(const bf8_t*)(&sB[frow * 64 + kk * 32 + fk]);
      #pragma unroll
      for (int mi = 0; mi < 2; ++mi) {
        const bf8_t af = *(const bf8_t*)(&sA[(wid * 32 + mi * 16 + frow) * 64 + kk * 32 + fk]);
        acc[mi] = __builtin_amdgcn_mfma_f32_16x16x32_bf16(bf, af, acc[mi], 0, 0, 0);
      }
    }
  }

  const int cg = (lane >> 4) * 4;
  #pragma unroll
  for (int mi = 0; mi < 2; ++mi) {
    const int r = row0 + wid * 32 + mi * 16 + frow;
    if (r < NROWS && cg < 12) {
      f4_t v = acc[mi];
      const f4_t bb = *(const f4_t*)(b3 + cg);  // cg in {0,4,8}: reads b3[0..11]
      v += bb;
      *(f4_t*)(out + (size_t)r * 12 + cg) = v;
    }
  }
}

// ---------------- host ----------------
extern "C" void kernel_launch(void* const* d_in, const int* in_sizes, int n_in,
                              void* d_out, int out_size, void* d_ws, size_t ws_size,
                              hipStream_t stream) {
  const float* mixer    = (const float*)d_in[0];
  const float* features = (const float*)d_in[1];
  const int*   sg_batch = (const int*)d_in[2];
  const int*   sg_map   = (const int*)d_in[3];
  const float* W0 = (const float*)d_in[4];  const float* b0 = (const float*)d_in[5];
  const float* W1 = (const float*)d_in[6];  const float* b1 = (const float*)d_in[7];
  const float* W2 = (const float*)d_in[8];  const float* b2 = (const float*)d_in[9];
  const float* W3 = (const float*)d_in[10]; const float* b3 = (const float*)d_in[11];
  float* out = (float*)d_out;

  char* wsp = (char*)d_ws;
  auto alloc = [&](size_t bytes) { char* p = wsp; wsp += (bytes + 255) & ~(size_t)255; return p; };
  unsigned short* h0  = (unsigned short*)alloc((size_t)MPAD * KD * 2);   // 66.7 MB
  unsigned short* h1  = (unsigned short*)alloc((size_t)MPAD * KD * 2);   // 66.7 MB
  unsigned short* Wt1 = (unsigned short*)alloc((size_t)NPW * KD * 2);
  unsigned short* Wt2 = (unsigned short*)alloc((size_t)NPW * KD * 2);
  unsigned short* Wt3 = (unsigned short*)alloc((size_t)16 * KD * 2);
  unsigned short* WTB = (unsigned short*)alloc((size_t)NPW * KA0 * 2);
  float* bp0   = (float*)alloc(KD * 4);
  float* bp1   = (float*)alloc(KD * 4);
  float* bp2   = (float*)alloc(KD * 4);
  float* fW0   = (float*)alloc((size_t)128 * KD * 4);
  int* counts  = (int*)alloc(NSEG * 4);
  // Cff (20.5 MB f32) and Abuf (12.8 MB bf16) alias h1's space: both are dead
  // before the first write to h1 (layer-1 GEMM output).
  float* Cff = (float*)h1;
  unsigned short* Abuf = (unsigned short*)((char*)h1 + ((size_t)MPAD * 128 * 4 + 255 & ~(size_t)255));

  // segment counts
  k_zero<<<(NSEG + 255) / 256, 256, 0, stream>>>(counts);
  k_count<<<(EN + 255) / 256, 256, 0, stream>>>(sg_map, counts);

  // Cf coefficient matrix
  k_zerof<<<(MPAD * 128 + 255) / 256, 256, 0, stream>>>(Cff, MPAD * 128);
  k_scatterCf<<<(EN + 255) / 256, 256, 0, stream>>>(sg_map, sg_batch, Cff);

  // weight prep
  k_flatW0<<<dim3(13, 16), 256, 0, stream>>>(mixer, W0, fW0);
  k_tpad<<<(NPW * KD + 255) / 256, 256, 0, stream>>>(W1, Wt1, 780, 780, NPW * KD);
  k_tpad<<<(NPW * KD + 255) / 256, 256, 0, stream>>>(W2, Wt2, 780, 780, NPW * KD);
  k_tpad<<<(16 * KD + 255) / 256, 256, 0, stream>>>(W3, Wt3, 12, 12, 16 * KD);
  k_padbias3<<<(3 * KD + 255) / 256, 256, 0, stream>>>(b0, b1, b2, bp0, bp1, bp2);
  k_buildB<<<(NPW * KA0 + 255) / 256, 256, 0, stream>>>(W0, fW0, WTB);

  // layer-0 operand A = [features | Cf | 0]
  k_buildA<<<(MPAD * KA0 + 255) / 256, 256, 0, stream>>>(features, counts, Cff, Abuf);

  // layer 0 as GEMM (K=160, BK=32) -> h0
  gemm_relu<KA0, 32><<<(MPAD / 128) * NT, 256, 0, stream>>>(Abuf, WTB, bp0, h0);

  // layers 1,2 (dense bf16 MFMA, K=832, BK=64) -> h1 -> h0
  gemm_relu<KD, 64><<<(MPAD / 128) * NT, 256, 0, stream>>>(h0, Wt1, bp1, h1);
  gemm_relu<KD, 64><<<(MPAD / 128) * NT, 256, 0, stream>>>(h1, Wt2, bp2, h0);

  // layer 3 -> out
  gemm_out<<<MPAD / 128, 256, 0, stream>>>(h0, Wt3, b3, out);
}

// Round 12
// 347.002 us; speedup vs baseline: 1.2236x; 1.0198x over previous
//
#include <hip/hip_runtime.h>

// Problem constants (fixed by setup_inputs)
#define BG    4        // num_graphs
#define TT    12       // timesteps
#define NN    10000    // nodes per graph
#define EN    200000   // membership entries
#define NSEG  40000    // n*B segments
#define NROWS 40000    // B*n output rows
#define MPAD  40064    // 313*128
#define KD    832      // padded in_dim (780 -> 832 = 13*64) ; also h* row stride
#define KA0   160      // padded K for layer0 GEMM: 12 features + 128 Cf + 20 zero
#define NPW   896      // padded N for weight tiles (7*128)
#define NT    7        // N-tiles per row panel (NPW/128)
#define KW3   896      // Wt3 row stride (padded to NPW so fused tiles never OOB)

typedef __attribute__((ext_vector_type(8))) short bf8_t;   // 8 bf16 (4 VGPR) MFMA A/B frag
typedef __attribute__((ext_vector_type(4))) float f4_t;    // 4 f32 MFMA C/D frag

__device__ __forceinline__ unsigned short f2bf(float x) {  // RNE f32->bf16
  unsigned int u = __float_as_uint(x);
  u += 0x7fffu + ((u >> 16) & 1u);
  return (unsigned short)(u >> 16);
}

#define GLDS16(src, dst) __builtin_amdgcn_global_load_lds( \
    (const __attribute__((address_space(1))) void*)(src),  \
    (__attribute__((address_space(3))) void*)(dst), 16, 0, 0)

#define LKW0 asm volatile("s_waitcnt lgkmcnt(0)" ::: "memory")
#define VMW0 asm volatile("s_waitcnt vmcnt(0)" ::: "memory")
#define SBAR0 __builtin_amdgcn_sched_barrier(0)

// ---------------- prep ----------------
// counts=0, Cff=0, out=b3 broadcast (one kernel, 3 flat ranges)
__global__ void k_init(int* __restrict__ counts, float* __restrict__ Cff,
                       float* __restrict__ out3, const float* __restrict__ b3) {
  int i = blockIdx.x * 256 + threadIdx.x;
  if (i < NSEG) counts[i] = 0;
  if (i < MPAD * 128) Cff[i] = 0.f;
  if (i < NROWS * 12) out3[i] = b3[i % 12];
}

__global__ void k_count(const int* __restrict__ mapper, int* __restrict__ counts) {
  int e = blockIdx.x * 256 + threadIdx.x;
  if (e < EN) atomicAdd(&counts[mapper[e]], 1);
}

// Cf scatter: entry e contributes 1 to Cff[r][batch[e]], r = output row of segment mapper[e]
__global__ void k_scatterCf(const int* __restrict__ mapper, const int* __restrict__ batch,
                            float* __restrict__ Cff) {
  int e = blockIdx.x * 256 + threadIdx.x;
  if (e < EN) {
    const int s = mapper[e];
    const int r = (s % BG) * NN + s / BG;   // inverse of s = (r%NN)*BG + r/NN
    atomicAdd(&Cff[(size_t)r * 128 + batch[e]], 1.0f);
  }
}

// A = [features(12) | Cf(128) | 0(20)] as bf16, [MPAD][KA0]
__global__ void k_buildA(const float* __restrict__ features, const int* __restrict__ counts,
                         const float* __restrict__ Cff, unsigned short* __restrict__ A) {
  int idx = blockIdx.x * 256 + threadIdx.x;
  if (idx >= MPAD * KA0) return;
  const int r = idx / KA0, c = idx - r * KA0;
  float v = 0.f;
  if (r < NROWS) {
    if (c < 12) {
      v = features[(size_t)r * TT + c];
    } else if (c < 140) {
      const int s = (r % NN) * BG + (r / NN);
      const int cnt = counts[s];
      const float inv = 1.f / (float)(cnt > 0 ? cnt : 1);
      v = Cff[(size_t)r * 128 + (c - 12)] * inv;
    }
  }
  A[idx] = f2bf(v);
}

// One kernel for all weight/bias prep:
//   [0,S1)            Wt1[n][k] = W1[k][n]   (NPW x KD)
//   [S1,2*S1)         Wt2[n][k] = W2[k][n]   (NPW x KD)
//   [2*S1, +S3)       Wt3[n][k] = W3[k][n]   (16 x KW3)
//   [.., +3*NPW)      bp0/bp1/bp2 (NPW wide, zero past 780)
//   [.., +S5)         WTB[n][k] = k<12 ? W0[k][n] : k<140 ? fW0[k-12][n] : 0  (NPW x KA0)
__global__ void k_prep(const float* __restrict__ W0, const float* __restrict__ fW0,
                       const float* __restrict__ W1, const float* __restrict__ W2,
                       const float* __restrict__ W3,
                       const float* __restrict__ b0, const float* __restrict__ b1,
                       const float* __restrict__ b2,
                       unsigned short* __restrict__ Wt1, unsigned short* __restrict__ Wt2,
                       unsigned short* __restrict__ Wt3,
                       float* __restrict__ bp0, float* __restrict__ bp1,
                       float* __restrict__ bp2, unsigned short* __restrict__ WTB) {
  constexpr int S1 = NPW * KD;
  constexpr int S3 = 16 * KW3;
  constexpr int SB = 3 * NPW;
  constexpr int S5 = NPW * KA0;
  int idx = blockIdx.x * 256 + threadIdx.x;
  if (idx < 2 * S1) {
    const int which = idx / S1, rem = idx - which * S1;
    const int n = rem / KD, k = rem - n * KD;
    const float* W = which ? W2 : W1;
    float v = (n < 780 && k < 780) ? W[(size_t)k * 780 + n] : 0.f;
    (which ? Wt2 : Wt1)[rem] = f2bf(v);
    return;
  }
  idx -= 2 * S1;
  if (idx < S3) {
    const int n = idx / KW3, k = idx - n * KW3;
    float v = (n < 12 && k < 780) ? W3[(size_t)k * 12 + n] : 0.f;
    Wt3[idx] = f2bf(v);
    return;
  }
  idx -= S3;
  if (idx < SB) {
    const int which = idx / NPW, c = idx - which * NPW;
    const float* src = which == 0 ? b0 : (which == 1 ? b1 : b2);
    float* dst = which == 0 ? bp0 : (which == 1 ? bp1 : bp2);
    dst[c] = (c < 780) ? src[c] : 0.f;
    return;
  }
  idx -= SB;
  if (idx < S5) {
    const int n = idx / KA0, k = idx - n * KA0;
    float v = 0.f;
    if (n < 780) {
      if (k < 12) v = W0[(size_t)k * 780 + n];
      else if (k < 140) v = fW0[(size_t)(k - 12) * KD + n];
    }
    WTB[idx] = f2bf(v);
  }
}

// flatW0[j][c] = sum_k flat[j][k] * W0[12+k][c], j<128, c<780 (0 for 780<=c<832)
// flat[j][t*64+f] = mixer_x[j%4][t][j/4][f]
// Split-K f32: grid (13 c-tiles x 16 j-tiles), block 256 = 64 c-lanes x 4 k-splits.
__global__ __launch_bounds__(256) void k_flatW0(const float* __restrict__ mixer,
                                                const float* __restrict__ W0,
                                                float* __restrict__ fW0) {
  __shared__ float sA[8][768];       // 24 KB: 8 A-rows
  __shared__ float sRed[4][64][9];   // 9.2 KB, pad 9 -> conflict-free
  const int tid = threadIdx.x;
  const int c0 = blockIdx.x * 64, j0 = blockIdx.y * 8;
  for (int i = tid; i < 8 * 768; i += 256) {
    int jj = i / 768;
    int k = i - jj * 768;
    int j = j0 + jj;
    int tt = k >> 6, ff = k & 63;
    sA[jj][k] = mixer[(((j & 3) * TT + tt) * 32 + (j >> 2)) * 64 + ff];
  }
  __syncthreads();
  const int cc = tid & 63, ks = tid >> 6;
  const int c = c0 + cc;
  float acc[8] = {};
  if (c < 780) {
    const float* wp = W0 + (size_t)(12 + ks * 192) * 780 + c;
    #pragma unroll 4
    for (int k = ks * 192; k < ks * 192 + 192; ++k) {
      const float w = *wp; wp += 780;
      #pragma unroll
      for (int jj = 0; jj < 8; ++jj) acc[jj] = fmaf(sA[jj][k], w, acc[jj]);
    }
  }
  #pragma unroll
  for (int jj = 0; jj < 8; ++jj) sRed[ks][cc][jj] = acc[jj];
  __syncthreads();
  for (int o = tid; o < 512; o += 256) {
    const int oc = o & 63, jj = o >> 6;
    const int wc = c0 + oc;
    if (wc < KD) {
      float s = sRed[0][oc][jj] + sRed[1][oc][jj] + sRed[2][oc][jj] + sRed[3][oc][jj];
      fW0[(size_t)(j0 + jj) * KD + wc] = s;  // cols >=780 stayed 0
    }
  }
}

// ---------------- dense layers: C = relu(A @ W + b), bf16 MFMA ----------------
// 128x128 tile, 4 waves (2x2), global_load_lds w=16, XCD swizzle (R6).
// K-loop = R10 structure (best measured): counted-vmcnt 2-deep pipeline + T2
// both-sides XOR swizzle (bank conflicts = 0). R11 kk-split reverted (null).
// R12: FUSE variant (layer 2): skip the global C write; stage the relu tile
// to LDS (XOR-swizzled), mini-GEMM vs Wt3 (16 x KW3), atomicAdd f32 partial
// rows into out (pre-initialized to b3 by k_init). Eliminates h0 write +
// gemm_out read + the gemm_out dispatch.
template<int KA, int BK, bool FUSE>
__global__ __launch_bounds__(256) void gemm_relu(
    const unsigned short* __restrict__ A, const unsigned short* __restrict__ WT,
    const float* __restrict__ bias, unsigned short* __restrict__ C,
    const unsigned short* __restrict__ W3t, float* __restrict__ out3) {
  constexpr int SEGR = BK / 8;                 // 16B chunks per row
  constexpr int MASK = SEGR - 1;
  constexpr int NISS = (128 * SEGR) / 256;     // per-thread issues per operand
  constexpr int NKT  = KA / BK;
  constexpr int NKK  = BK / 32;
  __shared__ unsigned short sA[2][128 * BK];
  __shared__ unsigned short sB[2][128 * BK];
  const int tid = threadIdx.x, lane = tid & 63, wid = tid >> 6;
  const int wm = wid >> 1, wn = wid & 1;

  // bijective XCD swizzle (nwg = 313*NT = 2191)
  const int nwg = gridDim.x;
  const int q = nwg >> 3, r8 = nwg & 7;
  const int xcd = blockIdx.x & 7, bidx = blockIdx.x >> 3;
  const int linear = (xcd < r8 ? xcd * (q + 1) : r8 * (q + 1) + (xcd - r8) * q) + bidx;
  const int rowtile = linear / NT, ntile = linear - rowtile * NT;

  const int row0 = rowtile * 128, n0 = ntile * 128;
  const char* gA = (const char*)A + (size_t)row0 * (KA * 2);
  const char* gB = (const char*)WT + (size_t)n0 * (KA * 2);
  const int frow = lane & 15;

  // t-invariant swizzled frag offsets (element units), compile-time indexed
  int offA[NKK][4], offB[NKK][4];
  #pragma unroll
  for (int kk = 0; kk < NKK; ++kk) {
    const int c16r = kk * 4 + (lane >> 4);
    #pragma unroll
    for (int i = 0; i < 4; ++i) {
      const int ra = wm * 64 + i * 16 + frow;
      const int rb = wn * 64 + i * 16 + frow;
      offA[kk][i] = ra * BK + ((c16r ^ (ra & MASK)) * 8);
      offB[kk][i] = rb * BK + ((c16r ^ (rb & MASK)) * 8);
    }
  }

  auto stage = [&](int b, int kt) {
    const int kb = kt * (BK * 2);
    #pragma unroll
    for (int L = 0; L < NISS; ++L) {
      const int seg = L * 256 + wid * 64 + lane;
      const int row = seg / SEGR, c16 = seg & MASK;
      const int c16s = c16 ^ (row & MASK);                 // pre-swizzled source
      const size_t go = (size_t)row * (KA * 2) + kb + c16s * 16;
      GLDS16(gA + go, (char*)sA[b] + seg * 16);
      GLDS16(gB + go, (char*)sB[b] + seg * 16);
    }
  };

  f4_t acc[4][4] = {};

  // prologue: tiles 0,1 in flight; wait tile 0
  stage(0, 0);
  stage(1, 1);
  if constexpr (BK == 64) asm volatile("s_waitcnt vmcnt(8)" ::: "memory");
  else                    asm volatile("s_waitcnt vmcnt(4)" ::: "memory");
  __builtin_amdgcn_s_barrier();

  #pragma unroll
  for (int t = 0; t < NKT; ++t) {
    const int cur = t & 1;
    bf8_t af[NKK][4], bfv[NKK][4];
    #pragma unroll
    for (int kk = 0; kk < NKK; ++kk) {
      #pragma unroll
      for (int i = 0; i < 4; ++i) {
        af[kk][i]  = *(const bf8_t*)(&sA[cur][offA[kk][i]]);
        bfv[kk][i] = *(const bf8_t*)(&sB[cur][offB[kk][i]]);
      }
    }
    if (t < NKT - 1) {
      LKW0;                               // own frag reads done (regs hold tile t)
      __builtin_amdgcn_s_barrier();       // all waves done reading buf[cur]
      SBAR0;                              // pin: no motion across the fence
      if (t + 2 < NKT) stage(cur, t + 2); // overwrite freed buf; stays in flight
    }
    __builtin_amdgcn_s_setprio(1);
    #pragma unroll
    for (int kk = 0; kk < NKK; ++kk)
      #pragma unroll
      for (int mi = 0; mi < 4; ++mi)
        #pragma unroll
        for (int ni = 0; ni < 4; ++ni)
          acc[mi][ni] = __builtin_amdgcn_mfma_f32_16x16x32_bf16(bfv[kk][ni], af[kk][mi], acc[mi][ni], 0, 0, 0);
    __builtin_amdgcn_s_setprio(0);
    if (t < NKT - 1) {
      if (t + 2 < NKT) {                  // wait tile t+1 only (t+2 in flight)
        if constexpr (BK == 64) asm volatile("s_waitcnt vmcnt(8)" ::: "memory");
        else                    asm volatile("s_waitcnt vmcnt(4)" ::: "memory");
      } else {
        VMW0;                             // last prefetch: full drain
      }
      __builtin_amdgcn_s_barrier();
    }
  }

  const int cq = (lane >> 4) * 4;
  if constexpr (!FUSE) {
    #pragma unroll
    for (int mi = 0; mi < 4; ++mi) {
      const int r = row0 + wm * 64 + mi * 16 + frow;
      unsigned short* crow = C + (size_t)r * KD;
      #pragma unroll
      for (int ni = 0; ni < 4; ++ni) {
        const int c = n0 + wn * 64 + ni * 16 + cq;
        if (c < KD) {  // wave-uniform per fragment
          f4_t v = acc[mi][ni];
          const f4_t bb = *(const f4_t*)(bias + c);
          float v0 = fmaxf(v[0] + bb[0], 0.f);
          float v1 = fmaxf(v[1] + bb[1], 0.f);
          float v2 = fmaxf(v[2] + bb[2], 0.f);
          float v3 = fmaxf(v[3] + bb[3], 0.f);
          uint2 pk;
          pk.x = (unsigned int)f2bf(v0) | ((unsigned int)f2bf(v1) << 16);
          pk.y = (unsigned int)f2bf(v2) | ((unsigned int)f2bf(v3) << 16);
          *(uint2*)(crow + c) = pk;
        }
      }
    }
  } else {
    // ---- fused layer-3 epilogue ----
    // 1) relu tile -> LDS [128][128] bf16 (32 KB, reuses sA region), swizzled
    //    byte ^= (row&7)<<4. Pad cols (c>=832): Wt rows are zero-padded and
    //    bias is NPW-wide zero, so relu(0+0)=0 -- write them too (no guard).
    unsigned short* sT = (unsigned short*)sA;
    __syncthreads();   // last tile's frag reads (all waves) complete before overwrite
    #pragma unroll
    for (int mi = 0; mi < 4; ++mi) {
      const int lr = wm * 64 + mi * 16 + frow;
      #pragma unroll
      for (int ni = 0; ni < 4; ++ni) {
        const int lc = wn * 64 + ni * 16 + cq;
        f4_t v = acc[mi][ni];
        const f4_t bb = *(const f4_t*)(bias + (n0 + lc));   // bias is NPW-wide
        float v0 = fmaxf(v[0] + bb[0], 0.f);
        float v1 = fmaxf(v[1] + bb[1], 0.f);
        float v2 = fmaxf(v[2] + bb[2], 0.f);
        float v3 = fmaxf(v[3] + bb[3], 0.f);
        uint2 pk;
        pk.x = (unsigned int)f2bf(v0) | ((unsigned int)f2bf(v1) << 16);
        pk.y = (unsigned int)f2bf(v2) | ((unsigned int)f2bf(v3) << 16);
        const int bo = (lr * 256 + lc * 2) ^ ((lr & 7) << 4);
        *(uint2*)((char*)sT + bo) = pk;
      }
    }
    __syncthreads();
    // 2) mini-GEMM: out_partial[128 rows][16] = tile[128][128] @ Wt3[n0:n0+128]^T
    //    (gemm_out operand convention: bf = Wt3 frag over 16 n-rows, af = tile rows)
    const int fk = (lane >> 4) * 8;
    f4_t acc2[2] = {};
    #pragma unroll
    for (int kk2 = 0; kk2 < 4; ++kk2) {
      const bf8_t bw = *(const bf8_t*)(W3t + (size_t)frow * KW3 + n0 + kk2 * 32 + fk);
      #pragma unroll
      for (int mi2 = 0; mi2 < 2; ++mi2) {
        const int lr2 = wid * 32 + mi2 * 16 + frow;
        const int bo = (lr2 * 256 + (kk2 * 32 + fk) * 2) ^ ((lr2 & 7) << 4);
        const bf8_t av = *(const bf8_t*)((char*)sT + bo);
        acc2[mi2] = __builtin_amdgcn_mfma_f32_16x16x32_bf16(bw, av, acc2[mi2], 0, 0, 0);
      }
    }
    // 3) atomic accumulate into out (pre-initialized to b3)
    #pragma unroll
    for (int mi2 = 0; mi2 < 2; ++mi2) {
      const int r2 = row0 + wid * 32 + mi2 * 16 + frow;
      if (r2 < NROWS && cq < 12) {
        float* orow = out3 + (size_t)r2 * 12 + cq;
        atomicAdd(&orow[0], acc2[mi2][0]);
        atomicAdd(&orow[1], acc2[mi2][1]);
        atomicAdd(&orow[2], acc2[mi2][2]);
        atomicAdd(&orow[3], acc2[mi2][3]);
      }
    }
  }
}

// ---------------- host ----------------
extern "C" void kernel_launch(void* const* d_in, const int* in_sizes, int n_in,
                              void* d_out, int out_size, void* d_ws, size_t ws_size,
                              hipStream_t stream) {
  const float* mixer    = (const float*)d_in[0];
  const float* features = (const float*)d_in[1];
  const int*   sg_batch = (const int*)d_in[2];
  const int*   sg_map   = (const int*)d_in[3];
  const float* W0 = (const float*)d_in[4];  const float* b0 = (const float*)d_in[5];
  const float* W1 = (const float*)d_in[6];  const float* b1 = (const float*)d_in[7];
  const float* W2 = (const float*)d_in[8];  const float* b2 = (const float*)d_in[9];
  const float* W3 = (const float*)d_in[10]; const float* b3 = (const float*)d_in[11];
  float* out = (float*)d_out;

  char* wsp = (char*)d_ws;
  auto alloc = [&](size_t bytes) { char* p = wsp; wsp += (bytes + 255) & ~(size_t)255; return p; };
  unsigned short* h0  = (unsigned short*)alloc((size_t)MPAD * KD * 2);   // 66.7 MB
  unsigned short* h1  = (unsigned short*)alloc((size_t)MPAD * KD * 2);   // 66.7 MB
  unsigned short* Wt1 = (unsigned short*)alloc((size_t)NPW * KD * 2);
  unsigned short* Wt2 = (unsigned short*)alloc((size_t)NPW * KD * 2);
  unsigned short* Wt3 = (unsigned short*)alloc((size_t)16 * KW3 * 2);
  unsigned short* WTB = (unsigned short*)alloc((size_t)NPW * KA0 * 2);
  float* bp0   = (float*)alloc(NPW * 4);
  float* bp1   = (float*)alloc(NPW * 4);
  float* bp2   = (float*)alloc(NPW * 4);
  float* fW0   = (float*)alloc((size_t)128 * KD * 4);
  int* counts  = (int*)alloc(NSEG * 4);
  // Cff (20.5 MB f32) and Abuf (12.8 MB bf16) alias h1's space: both are dead
  // before the first write to h1 (layer-1 GEMM output).
  float* Cff = (float*)h1;
  unsigned short* Abuf = (unsigned short*)((char*)h1 + ((size_t)MPAD * 128 * 4 + 255 & ~(size_t)255));

  // init: counts=0, Cff=0, out=b3
  k_init<<<(MPAD * 128 + 255) / 256, 256, 0, stream>>>(counts, Cff, out, b3);
  k_count<<<(EN + 255) / 256, 256, 0, stream>>>(sg_map, counts);
  k_scatterCf<<<(EN + 255) / 256, 256, 0, stream>>>(sg_map, sg_batch, Cff);

  // weight prep
  k_flatW0<<<dim3(13, 16), 256, 0, stream>>>(mixer, W0, fW0);
  {
    const int total = 2 * (NPW * KD) + 16 * KW3 + 3 * NPW + NPW * KA0;
    k_prep<<<(total + 255) / 256, 256, 0, stream>>>(W0, fW0, W1, W2, W3, b0, b1, b2,
                                                    Wt1, Wt2, Wt3, bp0, bp1, bp2, WTB);
  }

  // layer-0 operand A = [features | Cf | 0]
  k_buildA<<<(MPAD * KA0 + 255) / 256, 256, 0, stream>>>(features, counts, Cff, Abuf);

  // layer 0 as GEMM (K=160, BK=32) -> h0
  gemm_relu<KA0, 32, false><<<(MPAD / 128) * NT, 256, 0, stream>>>(Abuf, WTB, bp0, h0, nullptr, nullptr);

  // layer 1 (K=832, BK=64) -> h1
  gemm_relu<KD, 64, false><<<(MPAD / 128) * NT, 256, 0, stream>>>(h0, Wt1, bp1, h1, nullptr, nullptr);

  // layer 2 + fused layer 3 (K=832, BK=64): atomic out += tile @ Wt3
  gemm_relu<KD, 64, true><<<(MPAD / 128) * NT, 256, 0, stream>>>(h1, Wt2, bp2, nullptr, Wt3, out);
}

// Round 13
// 341.863 us; speedup vs baseline: 1.2420x; 1.0150x over previous
//
#include <hip/hip_runtime.h>

// Problem constants (fixed by setup_inputs)
#define BG    4        // num_graphs
#define TT    12       // timesteps
#define NN    10000    // nodes per graph
#define EN    200000   // membership entries
#define NSEG  40000    // n*B segments
#define NROWS 40000    // B*n output rows
#define MPAD  40064    // 313*128
#define KD    832      // padded in_dim (780 -> 832) ; also h* row stride
#define KA0   160      // padded K for layer0 GEMM: 12 features + 128 Cf + 20 zero
#define NPW   896      // padded N for weight tiles (7*128)
#define NT    7        // N-tiles per row panel (NPW/128)
#define KW3   896      // Wt3 row stride (padded to NPW so fused tiles never OOB)

typedef __attribute__((ext_vector_type(8))) short bf8_t;   // 8 bf16 (4 VGPR) MFMA A/B frag
typedef __attribute__((ext_vector_type(4))) float f4_t;    // 4 f32 MFMA C/D frag

__device__ __forceinline__ unsigned short f2bf(float x) {  // RNE f32->bf16
  unsigned int u = __float_as_uint(x);
  u += 0x7fffu + ((u >> 16) & 1u);
  return (unsigned short)(u >> 16);
}

#define GLDS16(src, dst) __builtin_amdgcn_global_load_lds( \
    (const __attribute__((address_space(1))) void*)(src),  \
    (__attribute__((address_space(3))) void*)(dst), 16, 0, 0)

#define LKW0 asm volatile("s_waitcnt lgkmcnt(0)" ::: "memory")
#define VMW0 asm volatile("s_waitcnt vmcnt(0)" ::: "memory")
#define VMW4 asm volatile("s_waitcnt vmcnt(4)" ::: "memory")
#define VMW8 asm volatile("s_waitcnt vmcnt(8)" ::: "memory")
#define SBAR0 __builtin_amdgcn_sched_barrier(0)

// ---------------- prep ----------------
// counts=0, Cff=0, out=b3 broadcast (one kernel, 3 flat ranges)
__global__ void k_init(int* __restrict__ counts, float* __restrict__ Cff,
                       float* __restrict__ out3, const float* __restrict__ b3) {
  int i = blockIdx.x * 256 + threadIdx.x;
  if (i < NSEG) counts[i] = 0;
  if (i < MPAD * 128) Cff[i] = 0.f;
  if (i < NROWS * 12) out3[i] = b3[i % 12];
}

__global__ void k_count(const int* __restrict__ mapper, int* __restrict__ counts) {
  int e = blockIdx.x * 256 + threadIdx.x;
  if (e < EN) atomicAdd(&counts[mapper[e]], 1);
}

// Cf scatter: entry e contributes 1 to Cff[r][batch[e]], r = output row of segment mapper[e]
__global__ void k_scatterCf(const int* __restrict__ mapper, const int* __restrict__ batch,
                            float* __restrict__ Cff) {
  int e = blockIdx.x * 256 + threadIdx.x;
  if (e < EN) {
    const int s = mapper[e];
    const int r = (s % BG) * NN + s / BG;   // inverse of s = (r%NN)*BG + r/NN
    atomicAdd(&Cff[(size_t)r * 128 + batch[e]], 1.0f);
  }
}

// A = [features(12) | Cf(128) | 0(20)] as bf16, [MPAD][KA0]
__global__ void k_buildA(const float* __restrict__ features, const int* __restrict__ counts,
                         const float* __restrict__ Cff, unsigned short* __restrict__ A) {
  int idx = blockIdx.x * 256 + threadIdx.x;
  if (idx >= MPAD * KA0) return;
  const int r = idx / KA0, c = idx - r * KA0;
  float v = 0.f;
  if (r < NROWS) {
    if (c < 12) {
      v = features[(size_t)r * TT + c];
    } else if (c < 140) {
      const int s = (r % NN) * BG + (r / NN);
      const int cnt = counts[s];
      const float inv = 1.f / (float)(cnt > 0 ? cnt : 1);
      v = Cff[(size_t)r * 128 + (c - 12)] * inv;
    }
  }
  A[idx] = f2bf(v);
}

// One kernel for all weight/bias prep (ranges: Wt1, Wt2, Wt3, biases, WTB)
__global__ void k_prep(const float* __restrict__ W0, const float* __restrict__ fW0,
                       const float* __restrict__ W1, const float* __restrict__ W2,
                       const float* __restrict__ W3,
                       const float* __restrict__ b0, const float* __restrict__ b1,
                       const float* __restrict__ b2,
                       unsigned short* __restrict__ Wt1, unsigned short* __restrict__ Wt2,
                       unsigned short* __restrict__ Wt3,
                       float* __restrict__ bp0, float* __restrict__ bp1,
                       float* __restrict__ bp2, unsigned short* __restrict__ WTB) {
  constexpr int S1 = NPW * KD;
  constexpr int S3 = 16 * KW3;
  constexpr int SB = 3 * NPW;
  constexpr int S5 = NPW * KA0;
  int idx = blockIdx.x * 256 + threadIdx.x;
  if (idx < 2 * S1) {
    const int which = idx / S1, rem = idx - which * S1;
    const int n = rem / KD, k = rem - n * KD;
    const float* W = which ? W2 : W1;
    float v = (n < 780 && k < 780) ? W[(size_t)k * 780 + n] : 0.f;
    (which ? Wt2 : Wt1)[rem] = f2bf(v);
    return;
  }
  idx -= 2 * S1;
  if (idx < S3) {
    const int n = idx / KW3, k = idx - n * KW3;
    float v = (n < 12 && k < 780) ? W3[(size_t)k * 12 + n] : 0.f;
    Wt3[idx] = f2bf(v);
    return;
  }
  idx -= S3;
  if (idx < SB) {
    const int which = idx / NPW, c = idx - which * NPW;
    const float* src = which == 0 ? b0 : (which == 1 ? b1 : b2);
    float* dst = which == 0 ? bp0 : (which == 1 ? bp1 : bp2);
    dst[c] = (c < 780) ? src[c] : 0.f;
    return;
  }
  idx -= SB;
  if (idx < S5) {
    const int n = idx / KA0, k = idx - n * KA0;
    float v = 0.f;
    if (n < 780) {
      if (k < 12) v = W0[(size_t)k * 780 + n];
      else if (k < 140) v = fW0[(size_t)(k - 12) * KD + n];
    }
    WTB[idx] = f2bf(v);
  }
}

// flatW0[j][c] = sum_k flat[j][k] * W0[12+k][c], j<128, c<780 (0 for 780<=c<832)
// flat[j][t*64+f] = mixer_x[j%4][t][j/4][f]
__global__ __launch_bounds__(256) void k_flatW0(const float* __restrict__ mixer,
                                                const float* __restrict__ W0,
                                                float* __restrict__ fW0) {
  __shared__ float sA[8][768];       // 24 KB: 8 A-rows
  __shared__ float sRed[4][64][9];   // 9.2 KB, pad 9 -> conflict-free
  const int tid = threadIdx.x;
  const int c0 = blockIdx.x * 64, j0 = blockIdx.y * 8;
  for (int i = tid; i < 8 * 768; i += 256) {
    int jj = i / 768;
    int k = i - jj * 768;
    int j = j0 + jj;
    int tt = k >> 6, ff = k & 63;
    sA[jj][k] = mixer[(((j & 3) * TT + tt) * 32 + (j >> 2)) * 64 + ff];
  }
  __syncthreads();
  const int cc = tid & 63, ks = tid >> 6;
  const int c = c0 + cc;
  float acc[8] = {};
  if (c < 780) {
    const float* wp = W0 + (size_t)(12 + ks * 192) * 780 + c;
    #pragma unroll 4
    for (int k = ks * 192; k < ks * 192 + 192; ++k) {
      const float w = *wp; wp += 780;
      #pragma unroll
      for (int jj = 0; jj < 8; ++jj) acc[jj] = fmaf(sA[jj][k], w, acc[jj]);
    }
  }
  #pragma unroll
  for (int jj = 0; jj < 8; ++jj) sRed[ks][cc][jj] = acc[jj];
  __syncthreads();
  for (int o = tid; o < 512; o += 256) {
    const int oc = o & 63, jj = o >> 6;
    const int wc = c0 + oc;
    if (wc < KD) {
      float s = sRed[0][oc][jj] + sRed[1][oc][jj] + sRed[2][oc][jj] + sRed[3][oc][jj];
      fW0[(size_t)(j0 + jj) * KD + wc] = s;  // cols >=780 stayed 0
    }
  }
}

// ---------------- dense layers: C = relu(A @ W + b), bf16 MFMA ----------------
// 128x128 tile, 4 waves (2x2), global_load_lds w=16, XCD swizzle (R6).
// R13: BK=32, 3-deep counted pipeline. LDS 48KB -> 3 blocks/CU (12 waves,
// 3/SIMD: 2x R12's TLP) and prefetch issued 3 tiles ahead (~450-600cyc
// coverage; h-reads largely L2/L3-resident). Known cost: 64B row stride ->
// inherent 4-way frag-read conflicts even swizzled; expected hidden by TLP.
// vmcnt (4 loads/stage): steady 8 (tiles t+2,t+3 in flight), tail 4 -> 0.
template<int KA, bool FUSE>
__global__ __launch_bounds__(256) void gemm_relu(
    const unsigned short* __restrict__ A, const unsigned short* __restrict__ WT,
    const float* __restrict__ bias, unsigned short* __restrict__ C,
    const unsigned short* __restrict__ W3t, float* __restrict__ out3) {
  constexpr int BK   = 32;
  constexpr int SEGR = BK / 8;                 // 4 x 16B chunks per row
  constexpr int MASK = SEGR - 1;
  constexpr int NISS = (128 * SEGR) / 256;     // 2 per-thread issues per operand
  constexpr int NKT  = KA / BK;
  constexpr int BUFB = 128 * BK * 2;           // 8KB per operand per buffer
  __shared__ char smem[3 * 2 * BUFB];          // 48KB: 3 x (sA 8K + sB 8K)
  const int tid = threadIdx.x, lane = tid & 63, wid = tid >> 6;
  const int wm = wid >> 1, wn = wid & 1;

  // bijective XCD swizzle (nwg = 313*NT = 2191)
  const int nwg = gridDim.x;
  const int q = nwg >> 3, r8 = nwg & 7;
  const int xcd = blockIdx.x & 7, bidx = blockIdx.x >> 3;
  const int linear = (xcd < r8 ? xcd * (q + 1) : r8 * (q + 1) + (xcd - r8) * q) + bidx;
  const int rowtile = linear / NT, ntile = linear - rowtile * NT;

  const int row0 = rowtile * 128, n0 = ntile * 128;
  const char* gA = (const char*)A + (size_t)row0 * (KA * 2);
  const char* gB = (const char*)WT + (size_t)n0 * (KA * 2);
  const int frow = lane & 15;

  // t-invariant swizzled frag offsets (byte units within a buffer)
  int offA[4], offB[4];
  {
    const int c16r = lane >> 4;                 // 0..3 (BK=32: one kk)
    #pragma unroll
    for (int i = 0; i < 4; ++i) {
      const int ra = wm * 64 + i * 16 + frow;
      const int rb = wn * 64 + i * 16 + frow;
      offA[i] = ra * (BK * 2) + ((c16r ^ (ra & MASK)) * 16);
      offB[i] = rb * (BK * 2) + ((c16r ^ (rb & MASK)) * 16);
    }
  }

  auto bufA = [&](int b) { return smem + b * 2 * BUFB; };
  auto bufB = [&](int b) { return smem + b * 2 * BUFB + BUFB; };

  auto stage = [&](int b, int kt) {
    const int kb = kt * (BK * 2);
    #pragma unroll
    for (int L = 0; L < NISS; ++L) {
      const int seg = L * 256 + wid * 64 + lane;
      const int row = seg / SEGR, c16 = seg & MASK;
      const int c16s = c16 ^ (row & MASK);                 // pre-swizzled source
      const size_t go = (size_t)row * (KA * 2) + kb + c16s * 16;
      GLDS16(gA + go, bufA(b) + seg * 16);
      GLDS16(gB + go, bufB(b) + seg * 16);
    }
  };

  f4_t acc[4][4] = {};

  // prologue: tiles 0,1,2 in flight; wait tile 0 (8 loads may remain)
  stage(0, 0);
  stage(1, 1);
  stage(2, 2);
  VMW8;
  __builtin_amdgcn_s_barrier();

  #pragma unroll
  for (int t = 0; t < NKT; ++t) {
    const int cur = t % 3;
    bf8_t af[4], bfv[4];
    #pragma unroll
    for (int i = 0; i < 4; ++i) {
      af[i]  = *(const bf8_t*)(bufA(cur) + offA[i]);
      bfv[i] = *(const bf8_t*)(bufB(cur) + offB[i]);
    }
    if (t < NKT - 1) {
      LKW0;                               // own frag reads done (regs hold tile t)
      __builtin_amdgcn_s_barrier();       // all waves done reading buf[cur]
      SBAR0;                              // pin: no motion across the fence
      if (t + 3 < NKT) stage(cur, t + 3); // overwrite freed buf; stays in flight
    } else {
      LKW0;
      SBAR0;
    }
    __builtin_amdgcn_s_setprio(1);
    #pragma unroll
    for (int mi = 0; mi < 4; ++mi)
      #pragma unroll
      for (int ni = 0; ni < 4; ++ni)
        acc[mi][ni] = __builtin_amdgcn_mfma_f32_16x16x32_bf16(bfv[ni], af[mi], acc[mi][ni], 0, 0, 0);
    __builtin_amdgcn_s_setprio(0);
    if (t < NKT - 1) {
      if (t + 3 < NKT)      { VMW8; }     // tiles t+2,t+3 stay in flight
      else if (t + 2 < NKT) { VMW4; }     // only t+2 in flight
      else                  { VMW0; }     // last prefetch: full drain
      __builtin_amdgcn_s_barrier();
    }
  }

  const int cq = (lane >> 4) * 4;
  if constexpr (!FUSE) {
    #pragma unroll
    for (int mi = 0; mi < 4; ++mi) {
      const int r = row0 + wm * 64 + mi * 16 + frow;
      unsigned short* crow = C + (size_t)r * KD;
      #pragma unroll
      for (int ni = 0; ni < 4; ++ni) {
        const int c = n0 + wn * 64 + ni * 16 + cq;
        if (c < KD) {  // wave-uniform per fragment
          f4_t v = acc[mi][ni];
          const f4_t bb = *(const f4_t*)(bias + c);
          float v0 = fmaxf(v[0] + bb[0], 0.f);
          float v1 = fmaxf(v[1] + bb[1], 0.f);
          float v2 = fmaxf(v[2] + bb[2], 0.f);
          float v3 = fmaxf(v[3] + bb[3], 0.f);
          uint2 pk;
          pk.x = (unsigned int)f2bf(v0) | ((unsigned int)f2bf(v1) << 16);
          pk.y = (unsigned int)f2bf(v2) | ((unsigned int)f2bf(v3) << 16);
          *(uint2*)(crow + c) = pk;
        }
      }
    }
  } else {
    // ---- fused layer-3 epilogue ----
    // relu tile -> LDS [128][128] bf16 (32 KB within smem), byte ^= (row&7)<<4.
    unsigned short* sT = (unsigned short*)smem;
    __syncthreads();   // all waves past their last frag reads before overwrite
    #pragma unroll
    for (int mi = 0; mi < 4; ++mi) {
      const int lr = wm * 64 + mi * 16 + frow;
      #pragma unroll
      for (int ni = 0; ni < 4; ++ni) {
        const int lc = wn * 64 + ni * 16 + cq;
        f4_t v = acc[mi][ni];
        const f4_t bb = *(const f4_t*)(bias + (n0 + lc));   // bias is NPW-wide
        float v0 = fmaxf(v[0] + bb[0], 0.f);
        float v1 = fmaxf(v[1] + bb[1], 0.f);
        float v2 = fmaxf(v[2] + bb[2], 0.f);
        float v3 = fmaxf(v[3] + bb[3], 0.f);
        uint2 pk;
        pk.x = (unsigned int)f2bf(v0) | ((unsigned int)f2bf(v1) << 16);
        pk.y = (unsigned int)f2bf(v2) | ((unsigned int)f2bf(v3) << 16);
        const int bo = (lr * 256 + lc * 2) ^ ((lr & 7) << 4);
        *(uint2*)((char*)sT + bo) = pk;
      }
    }
    __syncthreads();
    // mini-GEMM: out_partial[128][16] = tile[128][128] @ Wt3[n0:n0+128]^T
    const int fk = (lane >> 4) * 8;
    f4_t acc2[2] = {};
    #pragma unroll
    for (int kk2 = 0; kk2 < 4; ++kk2) {
      const bf8_t bw = *(const bf8_t*)(W3t + (size_t)frow * KW3 + n0 + kk2 * 32 + fk);
      #pragma unroll
      for (int mi2 = 0; mi2 < 2; ++mi2) {
        const int lr2 = wid * 32 + mi2 * 16 + frow;
        const int bo = (lr2 * 256 + (kk2 * 32 + fk) * 2) ^ ((lr2 & 7) << 4);
        const bf8_t av = *(const bf8_t*)((char*)sT + bo);
        acc2[mi2] = __builtin_amdgcn_mfma_f32_16x16x32_bf16(bw, av, acc2[mi2], 0, 0, 0);
      }
    }
    // atomic accumulate into out (pre-initialized to b3)
    #pragma unroll
    for (int mi2 = 0; mi2 < 2; ++mi2) {
      const int r2 = row0 + wid * 32 + mi2 * 16 + frow;
      if (r2 < NROWS && cq < 12) {
        float* orow = out3 + (size_t)r2 * 12 + cq;
        atomicAdd(&orow[0], acc2[mi2][0]);
        atomicAdd(&orow[1], acc2[mi2][1]);
        atomicAdd(&orow[2], acc2[mi2][2]);
        atomicAdd(&orow[3], acc2[mi2][3]);
      }
    }
  }
}

// ---------------- host ----------------
extern "C" void kernel_launch(void* const* d_in, const int* in_sizes, int n_in,
                              void* d_out, int out_size, void* d_ws, size_t ws_size,
                              hipStream_t stream) {
  const float* mixer    = (const float*)d_in[0];
  const float* features = (const float*)d_in[1];
  const int*   sg_batch = (const int*)d_in[2];
  const int*   sg_map   = (const int*)d_in[3];
  const float* W0 = (const float*)d_in[4];  const float* b0 = (const float*)d_in[5];
  const float* W1 = (const float*)d_in[6];  const float* b1 = (const float*)d_in[7];
  const float* W2 = (const float*)d_in[8];  const float* b2 = (const float*)d_in[9];
  const float* W3 = (const float*)d_in[10]; const float* b3 = (const float*)d_in[11];
  float* out = (float*)d_out;

  char* wsp = (char*)d_ws;
  auto alloc = [&](size_t bytes) { char* p = wsp; wsp += (bytes + 255) & ~(size_t)255; return p; };
  unsigned short* h0  = (unsigned short*)alloc((size_t)MPAD * KD * 2);   // 66.7 MB
  unsigned short* h1  = (unsigned short*)alloc((size_t)MPAD * KD * 2);   // 66.7 MB
  unsigned short* Wt1 = (unsigned short*)alloc((size_t)NPW * KD * 2);
  unsigned short* Wt2 = (unsigned short*)alloc((size_t)NPW * KD * 2);
  unsigned short* Wt3 = (unsigned short*)alloc((size_t)16 * KW3 * 2);
  unsigned short* WTB = (unsigned short*)alloc((size_t)NPW * KA0 * 2);
  float* bp0   = (float*)alloc(NPW * 4);
  float* bp1   = (float*)alloc(NPW * 4);
  float* bp2   = (float*)alloc(NPW * 4);
  float* fW0   = (float*)alloc((size_t)128 * KD * 4);
  int* counts  = (int*)alloc(NSEG * 4);
  // Cff (20.5 MB f32) and Abuf (12.8 MB bf16) alias h1's space: both are dead
  // before the first write to h1 (layer-1 GEMM output).
  float* Cff = (float*)h1;
  unsigned short* Abuf = (unsigned short*)((char*)h1 + ((size_t)MPAD * 128 * 4 + 255 & ~(size_t)255));

  // init: counts=0, Cff=0, out=b3
  k_init<<<(MPAD * 128 + 255) / 256, 256, 0, stream>>>(counts, Cff, out, b3);
  k_count<<<(EN + 255) / 256, 256, 0, stream>>>(sg_map, counts);
  k_scatterCf<<<(EN + 255) / 256, 256, 0, stream>>>(sg_map, sg_batch, Cff);

  // weight prep
  k_flatW0<<<dim3(13, 16), 256, 0, stream>>>(mixer, W0, fW0);
  {
    const int total = 2 * (NPW * KD) + 16 * KW3 + 3 * NPW + NPW * KA0;
    k_prep<<<(total + 255) / 256, 256, 0, stream>>>(W0, fW0, W1, W2, W3, b0, b1, b2,
                                                    Wt1, Wt2, Wt3, bp0, bp1, bp2, WTB);
  }

  // layer-0 operand A = [features | Cf | 0]
  k_buildA<<<(MPAD * KA0 + 255) / 256, 256, 0, stream>>>(features, counts, Cff, Abuf);

  // layer 0 as GEMM (K=160) -> h0
  gemm_relu<KA0, false><<<(MPAD / 128) * NT, 256, 0, stream>>>(Abuf, WTB, bp0, h0, nullptr, nullptr);

  // layer 1 (K=832) -> h1
  gemm_relu<KD, false><<<(MPAD / 128) * NT, 256, 0, stream>>>(h0, Wt1, bp1, h1, nullptr, nullptr);

  // layer 2 + fused layer 3 (K=832): atomic out += tile @ Wt3
  gemm_relu<KD, true><<<(MPAD / 128) * NT, 256, 0, stream>>>(h1, Wt2, bp2, nullptr, Wt3, out);
}